// Round 11
// baseline (618.069 us; speedup 1.0000x reference)
//
#include <hip/hip_runtime.h>
#include <math.h>

#define NN 50000
#define D 128
#define BM 32    // rows per block in sage_layer
#define LDR 132  // padded LDS row stride (floats): rt groups spread 8 banks apart
#define NB 49    // scan blocks: ceil(50000/1024)

// ---- CSR build ----------------------------------------------------------

__global__ void count_kernel(const int* __restrict__ e, int E, int* __restrict__ cnt) {
    int i = blockIdx.x * blockDim.x + threadIdx.x;
    if (i < E) atomicAdd(&cnt[e[E + i]], 1);
}

// 49 blocks x 256 threads, 4 elems/thread: block-local exclusive scan
__global__ __launch_bounds__(256) void scan_blocks_kernel(const int* __restrict__ cnt,
                                                          int* __restrict__ row_ptr,
                                                          int* __restrict__ bsum, int N) {
    __shared__ int wsum[4], woff[4];
    int t = threadIdx.x;
    int lane = t & 63, wave = t >> 6;
    int base = blockIdx.x * 1024 + t * 4;
    int4 v = make_int4(0, 0, 0, 0);
    if (base + 4 <= N) v = *(const int4*)(cnt + base);
    int s = v.x + v.y + v.z + v.w;
    int incl = s;
    for (int off = 1; off < 64; off <<= 1) {
        int u = __shfl_up(incl, off);
        if (lane >= off) incl += u;
    }
    if (lane == 63) wsum[wave] = incl;
    __syncthreads();
    if (t == 0) {
        int r = 0;
        #pragma unroll
        for (int w = 0; w < 4; ++w) { woff[w] = r; r += wsum[w]; }
    }
    __syncthreads();
    int excl = woff[wave] + incl - s;
    if (base + 4 <= N) {
        int4 rp;
        rp.x = excl;
        rp.y = rp.x + v.x;
        rp.z = rp.y + v.y;
        rp.w = rp.z + v.z;
        *(int4*)(row_ptr + base) = rp;
    }
    if (t == 255) bsum[blockIdx.x] = woff[3] + wsum[3];
}

// single tiny block: exclusive scan of the 49 block sums (in place)
__global__ __launch_bounds__(64) void scan_bsums_kernel(int* __restrict__ bsum, int nb) {
    int l = threadIdx.x;
    int v = (l < nb) ? bsum[l] : 0;
    int incl = v;
    for (int off = 1; off < 64; off <<= 1) {
        int u = __shfl_up(incl, off);
        if (l >= off) incl += u;
    }
    if (l < nb) bsum[l] = incl - v;
}

__global__ __launch_bounds__(256) void scan_add_kernel(const int* __restrict__ cnt,
                                                       int* __restrict__ row_ptr,
                                                       const int* __restrict__ bsum,
                                                       float* __restrict__ inv_cnt,
                                                       int N, int E) {
    int base = blockIdx.x * 1024 + threadIdx.x * 4;
    int off = bsum[blockIdx.x];
    if (base + 4 <= N) {
        int4 rp = *(int4*)(row_ptr + base);
        rp.x += off; rp.y += off; rp.z += off; rp.w += off;
        *(int4*)(row_ptr + base) = rp;
        int4 c = *(const int4*)(cnt + base);
        float4 ic;
        ic.x = 1.0f / fmaxf((float)c.x, 1.0f);
        ic.y = 1.0f / fmaxf((float)c.y, 1.0f);
        ic.z = 1.0f / fmaxf((float)c.z, 1.0f);
        ic.w = 1.0f / fmaxf((float)c.w, 1.0f);
        *(float4*)(inv_cnt + base) = ic;
    }
    if (blockIdx.x == 0 && threadIdx.x == 0) row_ptr[N] = E;
}

__global__ void scatter_kernel(const int* __restrict__ e, int E,
                               const int* __restrict__ row_ptr,
                               int* __restrict__ fill,
                               int* __restrict__ csr_src) {
    int i = blockIdx.x * blockDim.x + threadIdx.x;
    if (i < E) {
        int d = e[E + i];
        int pos = row_ptr[d] + atomicAdd(&fill[d], 1);
        csr_src[pos] = e[i];
    }
}

// ---- mean aggregation: one 32-lane group per node, float4 lanes ---------

__global__ __launch_bounds__(256) void aggregate_kernel(const float* __restrict__ h,
                                                        const int* __restrict__ row_ptr,
                                                        const int* __restrict__ csr_src,
                                                        const float* __restrict__ inv_cnt,
                                                        float* __restrict__ agg, int N) {
    int node = (int)((blockIdx.x * blockDim.x + threadIdx.x) >> 5);
    int l = threadIdx.x & 31;
    if (node >= N) return;
    const float4* h4 = (const float4*)h;
    int beg = row_ptr[node], end = row_ptr[node + 1];
    float4 a0 = make_float4(0.f, 0.f, 0.f, 0.f);
    float4 a1 = make_float4(0.f, 0.f, 0.f, 0.f);
    for (int base = beg; base < end; base += 32) {
        int idx = 0;
        if (base + l < end) idx = csr_src[base + l];
        int n = min(32, end - base);
        int j = 0;
        for (; j + 8 <= n; j += 8) {
            int s0 = __shfl(idx, j + 0, 32);
            int s1 = __shfl(idx, j + 1, 32);
            int s2 = __shfl(idx, j + 2, 32);
            int s3 = __shfl(idx, j + 3, 32);
            int s4 = __shfl(idx, j + 4, 32);
            int s5 = __shfl(idx, j + 5, 32);
            int s6 = __shfl(idx, j + 6, 32);
            int s7 = __shfl(idx, j + 7, 32);
            float4 v0 = h4[(size_t)s0 * 32 + l];
            float4 v1 = h4[(size_t)s1 * 32 + l];
            float4 v2 = h4[(size_t)s2 * 32 + l];
            float4 v3 = h4[(size_t)s3 * 32 + l];
            float4 v4 = h4[(size_t)s4 * 32 + l];
            float4 v5 = h4[(size_t)s5 * 32 + l];
            float4 v6 = h4[(size_t)s6 * 32 + l];
            float4 v7 = h4[(size_t)s7 * 32 + l];
            a0.x += v0.x + v2.x; a0.y += v0.y + v2.y; a0.z += v0.z + v2.z; a0.w += v0.w + v2.w;
            a1.x += v1.x + v3.x; a1.y += v1.y + v3.y; a1.z += v1.z + v3.z; a1.w += v1.w + v3.w;
            a0.x += v4.x + v6.x; a0.y += v4.y + v6.y; a0.z += v4.z + v6.z; a0.w += v4.w + v6.w;
            a1.x += v5.x + v7.x; a1.y += v5.y + v7.y; a1.z += v5.z + v7.z; a1.w += v5.w + v7.w;
        }
        for (; j < n; ++j) {
            int s = __shfl(idx, j, 32);
            float4 v = h4[(size_t)s * 32 + l];
            a0.x += v.x; a0.y += v.y; a0.z += v.z; a0.w += v.w;
        }
    }
    float iv = inv_cnt[node];
    ((float4*)agg)[(size_t)node * 32 + l] =
        make_float4((a0.x + a1.x) * iv, (a0.y + a1.y) * iv,
                    (a0.z + a1.z) * iv, (a0.w + a1.w) * iv);
}

// ---- fused dual-GEMM + bias + L2-normalize + (ReLU) ---------------------
// BM=32, thread tile 2 rows x 8 cols (ct=t&15 -> cols [8ct,8ct+8);
// rt=t>>4 -> rows [2rt,2rt+2)). Halves LDS read amplification vs 4-col
// tile; 34 KB LDS + 128-VGPR cap -> 4 blocks/CU, 4 waves/SIMD.
// LDS rows padded to 132 floats: the 4 rt-groups of a wave read banks
// {0,8,16,24}+k -> conflict-free broadcast reads.

__device__ __forceinline__ void fma4(float4& a, const float4& w, float s) {
    a.x += w.x * s; a.y += w.y * s; a.z += w.z * s; a.w += w.w * s;
}

__global__ __launch_bounds__(256, 4) void sage_layer_kernel(const float* __restrict__ x,
                                                            const float* __restrict__ agg,
                                                            const float* __restrict__ Wl,
                                                            const float* __restrict__ bl,
                                                            const float* __restrict__ Wr,
                                                            float* __restrict__ out,
                                                            int relu, int N) {
    __shared__ float sA[BM * LDR];   // 16.9 KB
    __shared__ float sX[BM * LDR];   // 16.9 KB
    int t = threadIdx.x;
    int row0 = blockIdx.x * BM;

    {
        const float4* a4 = (const float4*)agg;
        const float4* x4 = (const float4*)x;
        for (int i = t; i < BM * 32; i += 256) {
            int r = i >> 5;
            int c = i & 31;
            int gr = row0 + r;
            float4 va = make_float4(0.f, 0.f, 0.f, 0.f);
            float4 vx = va;
            if (gr < N) {
                va = a4[(size_t)gr * 32 + c];
                vx = x4[(size_t)gr * 32 + c];
            }
            *(float4*)(sA + r * LDR + c * 4) = va;
            *(float4*)(sX + r * LDR + c * 4) = vx;
        }
    }
    __syncthreads();

    int ct = t & 15;
    int rt = t >> 4;
    int r0 = rt * 2;

    float4 accA[2], accB[2];
    {
        float4 bA = ((const float4*)bl)[ct * 2];
        float4 bB = ((const float4*)bl)[ct * 2 + 1];
        accA[0] = bA; accA[1] = bA;
        accB[0] = bB; accB[1] = bB;
    }

    const float4* Wl4 = (const float4*)Wl;
    const float4* Wr4 = (const float4*)Wr;

    for (int k4 = 0; k4 < 32; ++k4) {
        int kb = k4 * 4;
        float4 wlA[4], wlB[4], wrA[4], wrB[4];
        #pragma unroll
        for (int kk = 0; kk < 4; ++kk) {
            wlA[kk] = Wl4[(kb + kk) * 32 + ct * 2];
            wlB[kk] = Wl4[(kb + kk) * 32 + ct * 2 + 1];
            wrA[kk] = Wr4[(kb + kk) * 32 + ct * 2];
            wrB[kk] = Wr4[(kb + kk) * 32 + ct * 2 + 1];
        }
        #pragma unroll
        for (int i = 0; i < 2; ++i) {
            float4 av = *(const float4*)(sA + (r0 + i) * LDR + k4 * 4);
            float4 xv = *(const float4*)(sX + (r0 + i) * LDR + k4 * 4);
            fma4(accA[i], wlA[0], av.x); fma4(accB[i], wlB[0], av.x);
            fma4(accA[i], wlA[1], av.y); fma4(accB[i], wlB[1], av.y);
            fma4(accA[i], wlA[2], av.z); fma4(accB[i], wlB[2], av.z);
            fma4(accA[i], wlA[3], av.w); fma4(accB[i], wlB[3], av.w);
            fma4(accA[i], wrA[0], xv.x); fma4(accB[i], wrB[0], xv.x);
            fma4(accA[i], wrA[1], xv.y); fma4(accB[i], wrB[1], xv.y);
            fma4(accA[i], wrA[2], xv.z); fma4(accB[i], wrB[2], xv.z);
            fma4(accA[i], wrA[3], xv.w); fma4(accB[i], wrB[3], xv.w);
        }
    }

    float4* out4 = (float4*)out;
    #pragma unroll
    for (int i = 0; i < 2; ++i) {
        float s = accA[i].x * accA[i].x + accA[i].y * accA[i].y
                + accA[i].z * accA[i].z + accA[i].w * accA[i].w
                + accB[i].x * accB[i].x + accB[i].y * accB[i].y
                + accB[i].z * accB[i].z + accB[i].w * accB[i].w;
        // reduce across the 16 col-threads of this row (xor masks < 16
        // stay within the 16-lane group)
        s += __shfl_xor(s, 1);
        s += __shfl_xor(s, 2);
        s += __shfl_xor(s, 4);
        s += __shfl_xor(s, 8);
        float inv = 1.0f / fmaxf(sqrtf(s), 1e-12f);
        float4 oA, oB;
        oA.x = accA[i].x * inv; oA.y = accA[i].y * inv;
        oA.z = accA[i].z * inv; oA.w = accA[i].w * inv;
        oB.x = accB[i].x * inv; oB.y = accB[i].y * inv;
        oB.z = accB[i].z * inv; oB.w = accB[i].w * inv;
        if (relu) {
            oA.x = fmaxf(oA.x, 0.f); oA.y = fmaxf(oA.y, 0.f);
            oA.z = fmaxf(oA.z, 0.f); oA.w = fmaxf(oA.w, 0.f);
            oB.x = fmaxf(oB.x, 0.f); oB.y = fmaxf(oB.y, 0.f);
            oB.z = fmaxf(oB.z, 0.f); oB.w = fmaxf(oB.w, 0.f);
        }
        int gr = row0 + r0 + i;
        if (gr < N) {
            out4[(size_t)gr * 32 + ct * 2]     = oA;
            out4[(size_t)gr * 32 + ct * 2 + 1] = oB;
        }
    }
}

// ---- final FC + softmax: LDS-tiled, 32 rows/block, 8 threads/row --------

__global__ __launch_bounds__(256, 4) void fc_softmax_kernel(const float* __restrict__ h,
                                                            const float* __restrict__ Wfc,
                                                            const float* __restrict__ bfc,
                                                            float* __restrict__ out, int N) {
    __shared__ float sH[32 * 132];  // 16.9 KB
    __shared__ float sW[128 * 40];  // 20.5 KB
    __shared__ float sB[40];
    int t = threadIdx.x;
    int row0 = blockIdx.x * 32;

    const float4* W4 = (const float4*)Wfc;
    float4* sW4 = (float4*)sW;
    for (int i = t; i < 1280; i += 256) sW4[i] = W4[i];
    if (t < 40) sB[t] = bfc[t];

    const float4* h4 = (const float4*)h;
    for (int i = t; i < 32 * 32; i += 256) {
        int r = i >> 5, c = i & 31;
        int gr = row0 + r;
        float4 v = make_float4(0.f, 0.f, 0.f, 0.f);
        if (gr < N) v = h4[(size_t)gr * 32 + c];
        *(float4*)(sH + r * 132 + c * 4) = v;
    }
    __syncthreads();

    int r = t >> 3, sub = t & 7;
    int c0 = sub * 5;
    float acc[5];
    #pragma unroll
    for (int i = 0; i < 5; ++i) acc[i] = sB[c0 + i];

    const float* hr = sH + r * 132;
    for (int k = 0; k < 128; ++k) {
        float hv = hr[k];
        const float* wk = sW + k * 40 + c0;
        #pragma unroll
        for (int i = 0; i < 5; ++i) acc[i] += hv * wk[i];
    }

    float m = acc[0];
    #pragma unroll
    for (int i = 1; i < 5; ++i) m = fmaxf(m, acc[i]);
    for (int off = 1; off < 8; off <<= 1) m = fmaxf(m, __shfl_xor(m, off));
    float s = 0.f;
    #pragma unroll
    for (int i = 0; i < 5; ++i) { acc[i] = expf(acc[i] - m); s += acc[i]; }
    for (int off = 1; off < 8; off <<= 1) s += __shfl_xor(s, off);
    float inv = 1.0f / s;

    int gr = row0 + r;
    if (gr < N) {
        #pragma unroll
        for (int i = 0; i < 5; ++i) out[(size_t)gr * 40 + c0 + i] = acc[i] * inv;
    }
}

// ---- launcher -----------------------------------------------------------

extern "C" void kernel_launch(void* const* d_in, const int* in_sizes, int n_in,
                              void* d_out, int out_size, void* d_ws, size_t ws_size,
                              hipStream_t stream) {
    const float* x   = (const float*)d_in[0];
    const int*   e   = (const int*)d_in[1];
    const float* W1l = (const float*)d_in[2];
    const float* b1  = (const float*)d_in[3];
    const float* W1r = (const float*)d_in[4];
    const float* W2l = (const float*)d_in[5];
    const float* b2  = (const float*)d_in[6];
    const float* W2r = (const float*)d_in[7];
    const float* W3l = (const float*)d_in[8];
    const float* b3  = (const float*)d_in[9];
    const float* W3r = (const float*)d_in[10];
    const float* Wfc = (const float*)d_in[11];
    const float* bfc = (const float*)d_in[12];
    float* out = (float*)d_out;

    const int N = NN;
    const int E = in_sizes[1] / 2;

    // 16B-aligned sections
    float* h1      = (float*)d_ws;
    float* h2      = h1 + (size_t)N * D;
    float* agg     = h2 + (size_t)N * D;
    float* inv_cnt = agg + (size_t)N * D;          // N floats (N%4==0)
    int*   row_ptr = (int*)(inv_cnt + N);          // N+4 ints
    int*   cnt     = row_ptr + (N + 4);            // N ints
    int*   fill    = cnt + N;                      // N ints
    int*   bsum    = fill + N;                     // 64 ints
    int*   csr_src = bsum + 64;                    // E ints

    hipMemsetAsync(cnt, 0, sizeof(int) * N, stream);
    hipMemsetAsync(fill, 0, sizeof(int) * N, stream);

    count_kernel<<<(E + 255) / 256, 256, 0, stream>>>(e, E, cnt);
    scan_blocks_kernel<<<NB, 256, 0, stream>>>(cnt, row_ptr, bsum, N);
    scan_bsums_kernel<<<1, 64, 0, stream>>>(bsum, NB);
    scan_add_kernel<<<NB, 256, 0, stream>>>(cnt, row_ptr, bsum, inv_cnt, N, E);
    scatter_kernel<<<(E + 255) / 256, 256, 0, stream>>>(e, E, row_ptr, fill, csr_src);

    int aggBlocks = (N * 32 + 255) / 256;
    int sageBlocks = (N + BM - 1) / BM;
    int fcBlocks = (N + 31) / 32;

    aggregate_kernel<<<aggBlocks, 256, 0, stream>>>(x, row_ptr, csr_src, inv_cnt, agg, N);
    sage_layer_kernel<<<sageBlocks, 256, 0, stream>>>(x, agg, W1l, b1, W1r, h1, 1, N);

    aggregate_kernel<<<aggBlocks, 256, 0, stream>>>(h1, row_ptr, csr_src, inv_cnt, agg, N);
    sage_layer_kernel<<<sageBlocks, 256, 0, stream>>>(h1, agg, W2l, b2, W2r, h2, 1, N);

    aggregate_kernel<<<aggBlocks, 256, 0, stream>>>(h2, row_ptr, csr_src, inv_cnt, agg, N);
    sage_layer_kernel<<<sageBlocks, 256, 0, stream>>>(h2, agg, W3l, b3, W3r, h1, 0, N);

    fc_softmax_kernel<<<fcBlocks, 256, 0, stream>>>(h1, Wfc, bfc, out, N);
}

// Round 12
// 279.052 us; speedup vs baseline: 2.2149x; 2.2149x over previous
//
#include <hip/hip_runtime.h>
#include <math.h>

#define NN 50000
#define D 128
#define NB 49    // scan blocks: ceil(50000/1024)

typedef __attribute__((ext_vector_type(8))) short bf16x8;
typedef __attribute__((ext_vector_type(4))) float f32x4;

__device__ __forceinline__ float bf2f(unsigned short u) {
    union { unsigned int i; float f; } c;
    c.i = ((unsigned int)u) << 16;
    return c.f;
}
__device__ __forceinline__ unsigned short f2bf(float f) {
    union { float f; unsigned int i; } c;
    c.f = f;
    unsigned int u = c.i;
    return (unsigned short)((u + 0x7FFFu + ((u >> 16) & 1u)) >> 16);
}

// ---- fp32 -> bf16 bulk convert ------------------------------------------

__global__ __launch_bounds__(256) void f32_to_bf16_kernel(const float* __restrict__ src,
                                                          unsigned short* __restrict__ dst,
                                                          int n4) {
    int i = blockIdx.x * 256 + threadIdx.x;
    if (i < n4) {
        float4 v = ((const float4*)src)[i];
        ushort4 o;
        o.x = f2bf(v.x); o.y = f2bf(v.y); o.z = f2bf(v.z); o.w = f2bf(v.w);
        ((ushort4*)dst)[i] = o;
    }
}

// ---- pack weight [128][128] fp32 -> MFMA B-fragment order bf16 ----------
// frag (ks,n): lane l elem e holds W[ks*32 + (l>>4)*8 + e][n*16 + (l&15)]
// linear: P[((ks*8+n)*64 + l)*8 + e]

__global__ __launch_bounds__(256) void pack_w_kernel(const float* __restrict__ W,
                                                     unsigned short* __restrict__ P) {
    int i = blockIdx.x * 256 + threadIdx.x;   // 0..16383
    int e = i & 7, l = (i >> 3) & 63, n = (i >> 9) & 7, ks = i >> 12;
    int k = ks * 32 + (l >> 4) * 8 + e;
    int col = n * 16 + (l & 15);
    P[i] = f2bf(W[k * D + col]);
}

// ---- CSR build ----------------------------------------------------------

__global__ void count_kernel(const int* __restrict__ e, int E, int* __restrict__ cnt) {
    int i = blockIdx.x * blockDim.x + threadIdx.x;
    if (i < E) atomicAdd(&cnt[e[E + i]], 1);
}

__global__ __launch_bounds__(256) void scan_blocks_kernel(const int* __restrict__ cnt,
                                                          int* __restrict__ row_ptr,
                                                          int* __restrict__ bsum, int N) {
    __shared__ int wsum[4], woff[4];
    int t = threadIdx.x;
    int lane = t & 63, wave = t >> 6;
    int base = blockIdx.x * 1024 + t * 4;
    int4 v = make_int4(0, 0, 0, 0);
    if (base + 4 <= N) v = *(const int4*)(cnt + base);
    int s = v.x + v.y + v.z + v.w;
    int incl = s;
    for (int off = 1; off < 64; off <<= 1) {
        int u = __shfl_up(incl, off);
        if (lane >= off) incl += u;
    }
    if (lane == 63) wsum[wave] = incl;
    __syncthreads();
    if (t == 0) {
        int r = 0;
        #pragma unroll
        for (int w = 0; w < 4; ++w) { woff[w] = r; r += wsum[w]; }
    }
    __syncthreads();
    int excl = woff[wave] + incl - s;
    if (base + 4 <= N) {
        int4 rp;
        rp.x = excl;
        rp.y = rp.x + v.x;
        rp.z = rp.y + v.y;
        rp.w = rp.z + v.z;
        *(int4*)(row_ptr + base) = rp;
    }
    if (t == 255) bsum[blockIdx.x] = woff[3] + wsum[3];
}

__global__ __launch_bounds__(64) void scan_bsums_kernel(int* __restrict__ bsum, int nb) {
    int l = threadIdx.x;
    int v = (l < nb) ? bsum[l] : 0;
    int incl = v;
    for (int off = 1; off < 64; off <<= 1) {
        int u = __shfl_up(incl, off);
        if (l >= off) incl += u;
    }
    if (l < nb) bsum[l] = incl - v;
}

__global__ __launch_bounds__(256) void scan_add_kernel(const int* __restrict__ cnt,
                                                       int* __restrict__ row_ptr,
                                                       const int* __restrict__ bsum,
                                                       float* __restrict__ inv_cnt,
                                                       int N, int E) {
    int base = blockIdx.x * 1024 + threadIdx.x * 4;
    int off = bsum[blockIdx.x];
    if (base + 4 <= N) {
        int4 rp = *(int4*)(row_ptr + base);
        rp.x += off; rp.y += off; rp.z += off; rp.w += off;
        *(int4*)(row_ptr + base) = rp;
        int4 c = *(const int4*)(cnt + base);
        float4 ic;
        ic.x = 1.0f / fmaxf((float)c.x, 1.0f);
        ic.y = 1.0f / fmaxf((float)c.y, 1.0f);
        ic.z = 1.0f / fmaxf((float)c.z, 1.0f);
        ic.w = 1.0f / fmaxf((float)c.w, 1.0f);
        *(float4*)(inv_cnt + base) = ic;
    }
    if (blockIdx.x == 0 && threadIdx.x == 0) row_ptr[N] = E;
}

__global__ void scatter_kernel(const int* __restrict__ e, int E,
                               const int* __restrict__ row_ptr,
                               int* __restrict__ fill,
                               int* __restrict__ csr_src) {
    int i = blockIdx.x * blockDim.x + threadIdx.x;
    if (i < E) {
        int d = e[E + i];
        int pos = row_ptr[d] + atomicAdd(&fill[d], 1);
        csr_src[pos] = e[i];
    }
}

// ---- mean aggregation on bf16 rows: 32-lane group per node --------------
// rows are 256 B; lane loads ushort4 (8 B), fp32 accumulate, bf16 store.

__device__ __forceinline__ void acc_bf4(float& x, float& y, float& z, float& w, ushort4 v) {
    x += bf2f(v.x); y += bf2f(v.y); z += bf2f(v.z); w += bf2f(v.w);
}

__global__ __launch_bounds__(256) void aggregate_kernel(const unsigned short* __restrict__ h,
                                                        const int* __restrict__ row_ptr,
                                                        const int* __restrict__ csr_src,
                                                        const float* __restrict__ inv_cnt,
                                                        unsigned short* __restrict__ agg, int N) {
    int node = (int)((blockIdx.x * blockDim.x + threadIdx.x) >> 5);
    int l = threadIdx.x & 31;
    if (node >= N) return;
    const ushort4* h4 = (const ushort4*)h;   // 32 ushort4 per row
    int beg = row_ptr[node], end = row_ptr[node + 1];
    float a0x = 0.f, a0y = 0.f, a0z = 0.f, a0w = 0.f;
    float a1x = 0.f, a1y = 0.f, a1z = 0.f, a1w = 0.f;
    for (int base = beg; base < end; base += 32) {
        int idx = 0;
        if (base + l < end) idx = csr_src[base + l];
        int n = min(32, end - base);
        int j = 0;
        for (; j + 8 <= n; j += 8) {
            int s0 = __shfl(idx, j + 0, 32);
            int s1 = __shfl(idx, j + 1, 32);
            int s2 = __shfl(idx, j + 2, 32);
            int s3 = __shfl(idx, j + 3, 32);
            int s4 = __shfl(idx, j + 4, 32);
            int s5 = __shfl(idx, j + 5, 32);
            int s6 = __shfl(idx, j + 6, 32);
            int s7 = __shfl(idx, j + 7, 32);
            ushort4 v0 = h4[(size_t)s0 * 32 + l];
            ushort4 v1 = h4[(size_t)s1 * 32 + l];
            ushort4 v2 = h4[(size_t)s2 * 32 + l];
            ushort4 v3 = h4[(size_t)s3 * 32 + l];
            ushort4 v4 = h4[(size_t)s4 * 32 + l];
            ushort4 v5 = h4[(size_t)s5 * 32 + l];
            ushort4 v6 = h4[(size_t)s6 * 32 + l];
            ushort4 v7 = h4[(size_t)s7 * 32 + l];
            acc_bf4(a0x, a0y, a0z, a0w, v0);
            acc_bf4(a1x, a1y, a1z, a1w, v1);
            acc_bf4(a0x, a0y, a0z, a0w, v2);
            acc_bf4(a1x, a1y, a1z, a1w, v3);
            acc_bf4(a0x, a0y, a0z, a0w, v4);
            acc_bf4(a1x, a1y, a1z, a1w, v5);
            acc_bf4(a0x, a0y, a0z, a0w, v6);
            acc_bf4(a1x, a1y, a1z, a1w, v7);
        }
        for (; j < n; ++j) {
            int s = __shfl(idx, j, 32);
            ushort4 v = h4[(size_t)s * 32 + l];
            acc_bf4(a0x, a0y, a0z, a0w, v);
        }
    }
    float iv = inv_cnt[node];
    ushort4 o;
    o.x = f2bf((a0x + a1x) * iv);
    o.y = f2bf((a0y + a1y) * iv);
    o.z = f2bf((a0z + a1z) * iv);
    o.w = f2bf((a0w + a1w) * iv);
    ((ushort4*)agg)[(size_t)node * 32 + l] = o;
}

// ---- MFMA dual-GEMM + bias + L2-normalize + (ReLU) ----------------------
// 64 rows/block, wave w owns rows [64b+16w, +16). Per wave: 8 C-frags
// (16x16, n=0..7), K loop = 4 ks-steps of agg x Wl + 4 of x x Wr.
// A frag: lane l holds A[l&15][(l>>4)*8 + e] of each 16x32 slice, read
// directly from global bf16 rows (16B/lane). B frags from packed weights.
// C/D layout (m89-verified): col = lane&15, row = (lane>>4)*4 + reg.

__global__ __launch_bounds__(256) void sage_mfma_kernel(const unsigned short* __restrict__ aggb,
                                                        const unsigned short* __restrict__ xb,
                                                        const unsigned short* __restrict__ wlp,
                                                        const unsigned short* __restrict__ wrp,
                                                        const float* __restrict__ bl,
                                                        unsigned short* __restrict__ outb,
                                                        float* __restrict__ outf,
                                                        int relu, int N) {
    int t = threadIdx.x;
    int w = t >> 6;
    int l = t & 63;
    int rlo = l & 15;
    int khi = l >> 4;
    int row0 = blockIdx.x * 64 + w * 16;
    int rowA = row0 + rlo;
    bool okA = rowA < N;

    f32x4 acc[8];
    #pragma unroll
    for (int n = 0; n < 8; ++n) {
        float b = bl[n * 16 + rlo];
        acc[n] = (f32x4){b, b, b, b};
    }

    const short* Ap = (const short*)aggb + (size_t)(okA ? rowA : 0) * D + khi * 8;
    const short* Xp = (const short*)xb   + (size_t)(okA ? rowA : 0) * D + khi * 8;
    const short* WL = (const short*)wlp + l * 8;
    const short* WR = (const short*)wrp + l * 8;
    const bf16x8 Z = {0, 0, 0, 0, 0, 0, 0, 0};

    #pragma unroll 1
    for (int ks = 0; ks < 4; ++ks) {
        bf16x8 a = okA ? *(const bf16x8*)(Ap + ks * 32) : Z;
        #pragma unroll
        for (int n = 0; n < 8; ++n) {
            bf16x8 b = *(const bf16x8*)(WL + (ks * 8 + n) * 512);
            acc[n] = __builtin_amdgcn_mfma_f32_16x16x32_bf16(a, b, acc[n], 0, 0, 0);
        }
    }
    #pragma unroll 1
    for (int ks = 0; ks < 4; ++ks) {
        bf16x8 a = okA ? *(const bf16x8*)(Xp + ks * 32) : Z;
        #pragma unroll
        for (int n = 0; n < 8; ++n) {
            bf16x8 b = *(const bf16x8*)(WR + (ks * 8 + n) * 512);
            acc[n] = __builtin_amdgcn_mfma_f32_16x16x32_bf16(a, b, acc[n], 0, 0, 0);
        }
    }

    // fused row L2-norm: lane holds rows khi*4+r (r=0..3), cols n*16+rlo
    #pragma unroll
    for (int r = 0; r < 4; ++r) {
        float s = 0.f;
        #pragma unroll
        for (int n = 0; n < 8; ++n) s += acc[n][r] * acc[n][r];
        s += __shfl_xor(s, 1);
        s += __shfl_xor(s, 2);
        s += __shfl_xor(s, 4);
        s += __shfl_xor(s, 8);
        float inv = 1.0f / fmaxf(sqrtf(s), 1e-12f);
        int gr = row0 + khi * 4 + r;
        if (gr < N) {
            if (outb) {
                #pragma unroll
                for (int n = 0; n < 8; ++n) {
                    float v = acc[n][r] * inv;
                    if (relu) v = fmaxf(v, 0.f);
                    outb[(size_t)gr * D + n * 16 + rlo] = f2bf(v);
                }
            } else {
                #pragma unroll
                for (int n = 0; n < 8; ++n) {
                    float v = acc[n][r] * inv;
                    outf[(size_t)gr * D + n * 16 + rlo] = v;
                }
            }
        }
    }
}

// ---- final FC + softmax: LDS-tiled, 32 rows/block, 8 threads/row --------

__global__ __launch_bounds__(256, 4) void fc_softmax_kernel(const float* __restrict__ h,
                                                            const float* __restrict__ Wfc,
                                                            const float* __restrict__ bfc,
                                                            float* __restrict__ out, int N) {
    __shared__ float sH[32 * 132];
    __shared__ float sW[128 * 40];
    __shared__ float sB[40];
    int t = threadIdx.x;
    int row0 = blockIdx.x * 32;

    const float4* W4 = (const float4*)Wfc;
    float4* sW4 = (float4*)sW;
    for (int i = t; i < 1280; i += 256) sW4[i] = W4[i];
    if (t < 40) sB[t] = bfc[t];

    const float4* h4 = (const float4*)h;
    for (int i = t; i < 32 * 32; i += 256) {
        int r = i >> 5, c = i & 31;
        int gr = row0 + r;
        float4 v = make_float4(0.f, 0.f, 0.f, 0.f);
        if (gr < N) v = h4[(size_t)gr * 32 + c];
        *(float4*)(sH + r * 132 + c * 4) = v;
    }
    __syncthreads();

    int r = t >> 3, sub = t & 7;
    int c0 = sub * 5;
    float acc[5];
    #pragma unroll
    for (int i = 0; i < 5; ++i) acc[i] = sB[c0 + i];

    const float* hr = sH + r * 132;
    for (int k = 0; k < 128; ++k) {
        float hv = hr[k];
        const float* wk = sW + k * 40 + c0;
        #pragma unroll
        for (int i = 0; i < 5; ++i) acc[i] += hv * wk[i];
    }

    float m = acc[0];
    #pragma unroll
    for (int i = 1; i < 5; ++i) m = fmaxf(m, acc[i]);
    for (int off = 1; off < 8; off <<= 1) m = fmaxf(m, __shfl_xor(m, off));
    float s = 0.f;
    #pragma unroll
    for (int i = 0; i < 5; ++i) { acc[i] = expf(acc[i] - m); s += acc[i]; }
    for (int off = 1; off < 8; off <<= 1) s += __shfl_xor(s, off);
    float inv = 1.0f / s;

    int gr = row0 + r;
    if (gr < N) {
        #pragma unroll
        for (int i = 0; i < 5; ++i) out[(size_t)gr * 40 + c0 + i] = acc[i] * inv;
    }
}

// ---- launcher -----------------------------------------------------------

extern "C" void kernel_launch(void* const* d_in, const int* in_sizes, int n_in,
                              void* d_out, int out_size, void* d_ws, size_t ws_size,
                              hipStream_t stream) {
    const float* x   = (const float*)d_in[0];
    const int*   e   = (const int*)d_in[1];
    const float* W1l = (const float*)d_in[2];
    const float* b1  = (const float*)d_in[3];
    const float* W1r = (const float*)d_in[4];
    const float* W2l = (const float*)d_in[5];
    const float* b2  = (const float*)d_in[6];
    const float* W2r = (const float*)d_in[7];
    const float* W3l = (const float*)d_in[8];
    const float* b3  = (const float*)d_in[9];
    const float* W3r = (const float*)d_in[10];
    const float* Wfc = (const float*)d_in[11];
    const float* bfc = (const float*)d_in[12];
    float* out = (float*)d_out;

    const int N = NN;
    const int E = in_sizes[1] / 2;

    unsigned char* p = (unsigned char*)d_ws;
    unsigned short* xb   = (unsigned short*)p; p += (size_t)N * D * 2;
    unsigned short* h1b  = (unsigned short*)p; p += (size_t)N * D * 2;
    unsigned short* h2b  = (unsigned short*)p; p += (size_t)N * D * 2;
    unsigned short* aggb = (unsigned short*)p; p += (size_t)N * D * 2;
    unsigned short* w1lp = (unsigned short*)p; p += 16384 * 2;
    unsigned short* w1rp = (unsigned short*)p; p += 16384 * 2;
    unsigned short* w2lp = (unsigned short*)p; p += 16384 * 2;
    unsigned short* w2rp = (unsigned short*)p; p += 16384 * 2;
    unsigned short* w3lp = (unsigned short*)p; p += 16384 * 2;
    unsigned short* w3rp = (unsigned short*)p; p += 16384 * 2;
    float* inv_cnt = (float*)p; p += (size_t)N * 4;
    int* row_ptr = (int*)p; p += (size_t)(N + 4) * 4;
    int* cnt  = (int*)p; p += (size_t)N * 4;
    int* fill = (int*)p; p += (size_t)N * 4;
    int* bsum = (int*)p; p += 64 * 4;
    int* csr_src = (int*)p;
    float* h3f = (float*)xb;   // overlays xb+h1b (dead by layer 3)

    hipMemsetAsync(cnt, 0, sizeof(int) * N, stream);
    hipMemsetAsync(fill, 0, sizeof(int) * N, stream);

    f32_to_bf16_kernel<<<(N * D / 4 + 255) / 256, 256, 0, stream>>>(x, xb, N * D / 4);
    pack_w_kernel<<<64, 256, 0, stream>>>(W1l, w1lp);
    pack_w_kernel<<<64, 256, 0, stream>>>(W1r, w1rp);
    pack_w_kernel<<<64, 256, 0, stream>>>(W2l, w2lp);
    pack_w_kernel<<<64, 256, 0, stream>>>(W2r, w2rp);
    pack_w_kernel<<<64, 256, 0, stream>>>(W3l, w3lp);
    pack_w_kernel<<<64, 256, 0, stream>>>(W3r, w3rp);

    count_kernel<<<(E + 255) / 256, 256, 0, stream>>>(e, E, cnt);
    scan_blocks_kernel<<<NB, 256, 0, stream>>>(cnt, row_ptr, bsum, N);
    scan_bsums_kernel<<<1, 64, 0, stream>>>(bsum, NB);
    scan_add_kernel<<<NB, 256, 0, stream>>>(cnt, row_ptr, bsum, inv_cnt, N, E);
    scatter_kernel<<<(E + 255) / 256, 256, 0, stream>>>(e, E, row_ptr, fill, csr_src);

    int aggBlocks = (N * 32 + 255) / 256;
    int sageBlocks = (N + 63) / 64;
    int fcBlocks = (N + 31) / 32;

    aggregate_kernel<<<aggBlocks, 256, 0, stream>>>(xb, row_ptr, csr_src, inv_cnt, aggb, N);
    sage_mfma_kernel<<<sageBlocks, 256, 0, stream>>>(aggb, xb, w1lp, w1rp, b1,
                                                     h1b, nullptr, 1, N);

    aggregate_kernel<<<aggBlocks, 256, 0, stream>>>(h1b, row_ptr, csr_src, inv_cnt, aggb, N);
    sage_mfma_kernel<<<sageBlocks, 256, 0, stream>>>(aggb, h1b, w2lp, w2rp, b2,
                                                     h2b, nullptr, 1, N);

    aggregate_kernel<<<aggBlocks, 256, 0, stream>>>(h2b, row_ptr, csr_src, inv_cnt, aggb, N);
    sage_mfma_kernel<<<sageBlocks, 256, 0, stream>>>(aggb, h2b, w3lp, w3rp, b3,
                                                     nullptr, h3f, 0, N);

    fc_softmax_kernel<<<fcBlocks, 256, 0, stream>>>(h3f, Wfc, bfc, out, N);
}

// Round 13
// 273.968 us; speedup vs baseline: 2.2560x; 1.0186x over previous
//
#include <hip/hip_runtime.h>
#include <math.h>

#define NN 50000
#define D 128
#define NB 49    // scan blocks: ceil(50000/1024)

typedef __attribute__((ext_vector_type(8))) short bf16x8;
typedef __attribute__((ext_vector_type(4))) float f32x4;

__device__ __forceinline__ float bf2f(unsigned short u) {
    union { unsigned int i; float f; } c;
    c.i = ((unsigned int)u) << 16;
    return c.f;
}
__device__ __forceinline__ unsigned short f2bf(float f) {
    union { float f; unsigned int i; } c;
    c.f = f;
    unsigned int u = c.i;
    return (unsigned short)((u + 0x7FFFu + ((u >> 16) & 1u)) >> 16);
}

// ---- fp32 -> bf16 bulk convert ------------------------------------------

__global__ __launch_bounds__(256) void f32_to_bf16_kernel(const float* __restrict__ src,
                                                          unsigned short* __restrict__ dst,
                                                          int n4) {
    int i = blockIdx.x * 256 + threadIdx.x;
    if (i < n4) {
        float4 v = ((const float4*)src)[i];
        ushort4 o;
        o.x = f2bf(v.x); o.y = f2bf(v.y); o.z = f2bf(v.z); o.w = f2bf(v.w);
        ((ushort4*)dst)[i] = o;
    }
}

// ---- pack weight [128][128] fp32 -> MFMA B-fragment order bf16 ----------
// frag (ks,n): lane l elem e holds W[ks*32 + (l>>4)*8 + e][n*16 + (l&15)]

__global__ __launch_bounds__(256) void pack_w_kernel(const float* __restrict__ W,
                                                     unsigned short* __restrict__ P) {
    int i = blockIdx.x * 256 + threadIdx.x;   // 0..16383
    int e = i & 7, l = (i >> 3) & 63, n = (i >> 9) & 7, ks = i >> 12;
    int k = ks * 32 + (l >> 4) * 8 + e;
    int col = n * 16 + (l & 15);
    P[i] = f2bf(W[k * D + col]);
}

// ---- CSR build ----------------------------------------------------------

__global__ __launch_bounds__(256) void count_kernel(const int* __restrict__ e, int E,
                                                    int* __restrict__ cnt) {
    int i4 = (blockIdx.x * 256 + threadIdx.x) * 4;
    if (i4 + 4 <= E) {
        int4 d = *(const int4*)(e + E + i4);
        atomicAdd(&cnt[d.x], 1);
        atomicAdd(&cnt[d.y], 1);
        atomicAdd(&cnt[d.z], 1);
        atomicAdd(&cnt[d.w], 1);
    } else {
        for (int i = i4; i < E; ++i) atomicAdd(&cnt[e[E + i]], 1);
    }
}

__global__ __launch_bounds__(256) void scan_blocks_kernel(const int* __restrict__ cnt,
                                                          int* __restrict__ row_ptr,
                                                          int* __restrict__ bsum, int N) {
    __shared__ int wsum[4], woff[4];
    int t = threadIdx.x;
    int lane = t & 63, wave = t >> 6;
    int base = blockIdx.x * 1024 + t * 4;
    int4 v = make_int4(0, 0, 0, 0);
    if (base + 4 <= N) v = *(const int4*)(cnt + base);
    int s = v.x + v.y + v.z + v.w;
    int incl = s;
    for (int off = 1; off < 64; off <<= 1) {
        int u = __shfl_up(incl, off);
        if (lane >= off) incl += u;
    }
    if (lane == 63) wsum[wave] = incl;
    __syncthreads();
    if (t == 0) {
        int r = 0;
        #pragma unroll
        for (int w = 0; w < 4; ++w) { woff[w] = r; r += wsum[w]; }
    }
    __syncthreads();
    int excl = woff[wave] + incl - s;
    if (base + 4 <= N) {
        int4 rp;
        rp.x = excl;
        rp.y = rp.x + v.x;
        rp.z = rp.y + v.y;
        rp.w = rp.z + v.z;
        *(int4*)(row_ptr + base) = rp;
    }
    if (t == 255) bsum[blockIdx.x] = woff[3] + wsum[3];
}

__global__ __launch_bounds__(64) void scan_bsums_kernel(int* __restrict__ bsum, int nb) {
    int l = threadIdx.x;
    int v = (l < nb) ? bsum[l] : 0;
    int incl = v;
    for (int off = 1; off < 64; off <<= 1) {
        int u = __shfl_up(incl, off);
        if (l >= off) incl += u;
    }
    if (l < nb) bsum[l] = incl - v;
}

// adds block offsets, emits inv_cnt, and initializes fill = row_ptr
__global__ __launch_bounds__(256) void scan_add_kernel(const int* __restrict__ cnt,
                                                       int* __restrict__ row_ptr,
                                                       const int* __restrict__ bsum,
                                                       float* __restrict__ inv_cnt,
                                                       int* __restrict__ fill,
                                                       int N, int E) {
    int base = blockIdx.x * 1024 + threadIdx.x * 4;
    int off = bsum[blockIdx.x];
    if (base + 4 <= N) {
        int4 rp = *(int4*)(row_ptr + base);
        rp.x += off; rp.y += off; rp.z += off; rp.w += off;
        *(int4*)(row_ptr + base) = rp;
        *(int4*)(fill + base) = rp;
        int4 c = *(const int4*)(cnt + base);
        float4 ic;
        ic.x = 1.0f / fmaxf((float)c.x, 1.0f);
        ic.y = 1.0f / fmaxf((float)c.y, 1.0f);
        ic.z = 1.0f / fmaxf((float)c.z, 1.0f);
        ic.w = 1.0f / fmaxf((float)c.w, 1.0f);
        *(float4*)(inv_cnt + base) = ic;
    }
    if (blockIdx.x == 0 && threadIdx.x == 0) row_ptr[N] = E;
}

__global__ __launch_bounds__(256) void scatter_kernel(const int* __restrict__ e, int E,
                                                      int* __restrict__ fill,
                                                      unsigned short* __restrict__ csr_src) {
    int i4 = (blockIdx.x * 256 + threadIdx.x) * 4;
    if (i4 + 4 <= E) {
        int4 s = *(const int4*)(e + i4);
        int4 d = *(const int4*)(e + E + i4);
        csr_src[atomicAdd(&fill[d.x], 1)] = (unsigned short)s.x;
        csr_src[atomicAdd(&fill[d.y], 1)] = (unsigned short)s.y;
        csr_src[atomicAdd(&fill[d.z], 1)] = (unsigned short)s.z;
        csr_src[atomicAdd(&fill[d.w], 1)] = (unsigned short)s.w;
    } else {
        for (int i = i4; i < E; ++i) {
            int dd = e[E + i];
            csr_src[atomicAdd(&fill[dd], 1)] = (unsigned short)e[i];
        }
    }
}

// ---- mean aggregation on bf16 rows: 32-lane group per node --------------

__device__ __forceinline__ void acc_bf4(float& x, float& y, float& z, float& w, ushort4 v) {
    x += bf2f(v.x); y += bf2f(v.y); z += bf2f(v.z); w += bf2f(v.w);
}

__global__ __launch_bounds__(256) void aggregate_kernel(const unsigned short* __restrict__ h,
                                                        const int* __restrict__ row_ptr,
                                                        const unsigned short* __restrict__ csr_src,
                                                        const float* __restrict__ inv_cnt,
                                                        unsigned short* __restrict__ agg, int N) {
    int node = (int)((blockIdx.x * blockDim.x + threadIdx.x) >> 5);
    int l = threadIdx.x & 31;
    if (node >= N) return;
    const ushort4* h4 = (const ushort4*)h;   // 32 ushort4 per row
    int beg = row_ptr[node], end = row_ptr[node + 1];
    float a0x = 0.f, a0y = 0.f, a0z = 0.f, a0w = 0.f;
    float a1x = 0.f, a1y = 0.f, a1z = 0.f, a1w = 0.f;
    for (int base = beg; base < end; base += 32) {
        int idx = 0;
        if (base + l < end) idx = csr_src[base + l];
        int n = min(32, end - base);
        int j = 0;
        for (; j + 8 <= n; j += 8) {
            int s0 = __shfl(idx, j + 0, 32);
            int s1 = __shfl(idx, j + 1, 32);
            int s2 = __shfl(idx, j + 2, 32);
            int s3 = __shfl(idx, j + 3, 32);
            int s4 = __shfl(idx, j + 4, 32);
            int s5 = __shfl(idx, j + 5, 32);
            int s6 = __shfl(idx, j + 6, 32);
            int s7 = __shfl(idx, j + 7, 32);
            ushort4 v0 = h4[(size_t)s0 * 32 + l];
            ushort4 v1 = h4[(size_t)s1 * 32 + l];
            ushort4 v2 = h4[(size_t)s2 * 32 + l];
            ushort4 v3 = h4[(size_t)s3 * 32 + l];
            ushort4 v4 = h4[(size_t)s4 * 32 + l];
            ushort4 v5 = h4[(size_t)s5 * 32 + l];
            ushort4 v6 = h4[(size_t)s6 * 32 + l];
            ushort4 v7 = h4[(size_t)s7 * 32 + l];
            acc_bf4(a0x, a0y, a0z, a0w, v0);
            acc_bf4(a1x, a1y, a1z, a1w, v1);
            acc_bf4(a0x, a0y, a0z, a0w, v2);
            acc_bf4(a1x, a1y, a1z, a1w, v3);
            acc_bf4(a0x, a0y, a0z, a0w, v4);
            acc_bf4(a1x, a1y, a1z, a1w, v5);
            acc_bf4(a0x, a0y, a0z, a0w, v6);
            acc_bf4(a1x, a1y, a1z, a1w, v7);
        }
        for (; j < n; ++j) {
            int s = __shfl(idx, j, 32);
            ushort4 v = h4[(size_t)s * 32 + l];
            acc_bf4(a0x, a0y, a0z, a0w, v);
        }
    }
    float iv = inv_cnt[node];
    ushort4 o;
    o.x = f2bf((a0x + a1x) * iv);
    o.y = f2bf((a0y + a1y) * iv);
    o.z = f2bf((a0z + a1z) * iv);
    o.w = f2bf((a0w + a1w) * iv);
    ((ushort4*)agg)[(size_t)node * 32 + l] = o;
}

// ---- MFMA dual-GEMM + bias + L2-normalize + (ReLU) ----------------------
// 64 rows/block, wave w owns rows [64b+16w, +16). C/D layout (m89):
// col = lane&15, row = (lane>>4)*4 + reg.

__global__ __launch_bounds__(256) void sage_mfma_kernel(const unsigned short* __restrict__ aggb,
                                                        const unsigned short* __restrict__ xb,
                                                        const unsigned short* __restrict__ wlp,
                                                        const unsigned short* __restrict__ wrp,
                                                        const float* __restrict__ bl,
                                                        unsigned short* __restrict__ outb,
                                                        float* __restrict__ outf,
                                                        int relu, int N) {
    int t = threadIdx.x;
    int w = t >> 6;
    int l = t & 63;
    int rlo = l & 15;
    int khi = l >> 4;
    int row0 = blockIdx.x * 64 + w * 16;
    int rowA = row0 + rlo;
    bool okA = rowA < N;

    f32x4 acc[8];
    #pragma unroll
    for (int n = 0; n < 8; ++n) {
        float b = bl[n * 16 + rlo];
        acc[n] = (f32x4){b, b, b, b};
    }

    const short* Ap = (const short*)aggb + (size_t)(okA ? rowA : 0) * D + khi * 8;
    const short* Xp = (const short*)xb   + (size_t)(okA ? rowA : 0) * D + khi * 8;
    const short* WL = (const short*)wlp + l * 8;
    const short* WR = (const short*)wrp + l * 8;
    const bf16x8 Z = {0, 0, 0, 0, 0, 0, 0, 0};

    #pragma unroll 1
    for (int ks = 0; ks < 4; ++ks) {
        bf16x8 a = okA ? *(const bf16x8*)(Ap + ks * 32) : Z;
        #pragma unroll
        for (int n = 0; n < 8; ++n) {
            bf16x8 b = *(const bf16x8*)(WL + (ks * 8 + n) * 512);
            acc[n] = __builtin_amdgcn_mfma_f32_16x16x32_bf16(a, b, acc[n], 0, 0, 0);
        }
    }
    #pragma unroll 1
    for (int ks = 0; ks < 4; ++ks) {
        bf16x8 a = okA ? *(const bf16x8*)(Xp + ks * 32) : Z;
        #pragma unroll
        for (int n = 0; n < 8; ++n) {
            bf16x8 b = *(const bf16x8*)(WR + (ks * 8 + n) * 512);
            acc[n] = __builtin_amdgcn_mfma_f32_16x16x32_bf16(a, b, acc[n], 0, 0, 0);
        }
    }

    #pragma unroll
    for (int r = 0; r < 4; ++r) {
        float s = 0.f;
        #pragma unroll
        for (int n = 0; n < 8; ++n) s += acc[n][r] * acc[n][r];
        s += __shfl_xor(s, 1);
        s += __shfl_xor(s, 2);
        s += __shfl_xor(s, 4);
        s += __shfl_xor(s, 8);
        float inv = 1.0f / fmaxf(sqrtf(s), 1e-12f);
        int gr = row0 + khi * 4 + r;
        if (gr < N) {
            if (outb) {
                #pragma unroll
                for (int n = 0; n < 8; ++n) {
                    float v = acc[n][r] * inv;
                    if (relu) v = fmaxf(v, 0.f);
                    outb[(size_t)gr * D + n * 16 + rlo] = f2bf(v);
                }
            } else {
                #pragma unroll
                for (int n = 0; n < 8; ++n) {
                    float v = acc[n][r] * inv;
                    outf[(size_t)gr * D + n * 16 + rlo] = v;
                }
            }
        }
    }
}

// ---- final FC + softmax: LDS-tiled, 32 rows/block, 8 threads/row --------

__global__ __launch_bounds__(256, 4) void fc_softmax_kernel(const float* __restrict__ h,
                                                            const float* __restrict__ Wfc,
                                                            const float* __restrict__ bfc,
                                                            float* __restrict__ out, int N) {
    __shared__ float sH[32 * 132];
    __shared__ float sW[128 * 40];
    __shared__ float sB[40];
    int t = threadIdx.x;
    int row0 = blockIdx.x * 32;

    const float4* W4 = (const float4*)Wfc;
    float4* sW4 = (float4*)sW;
    for (int i = t; i < 1280; i += 256) sW4[i] = W4[i];
    if (t < 40) sB[t] = bfc[t];

    const float4* h4 = (const float4*)h;
    for (int i = t; i < 32 * 32; i += 256) {
        int r = i >> 5, c = i & 31;
        int gr = row0 + r;
        float4 v = make_float4(0.f, 0.f, 0.f, 0.f);
        if (gr < N) v = h4[(size_t)gr * 32 + c];
        *(float4*)(sH + r * 132 + c * 4) = v;
    }
    __syncthreads();

    int r = t >> 3, sub = t & 7;
    int c0 = sub * 5;
    float acc[5];
    #pragma unroll
    for (int i = 0; i < 5; ++i) acc[i] = sB[c0 + i];

    const float* hr = sH + r * 132;
    for (int k = 0; k < 128; ++k) {
        float hv = hr[k];
        const float* wk = sW + k * 40 + c0;
        #pragma unroll
        for (int i = 0; i < 5; ++i) acc[i] += hv * wk[i];
    }

    float m = acc[0];
    #pragma unroll
    for (int i = 1; i < 5; ++i) m = fmaxf(m, acc[i]);
    for (int off = 1; off < 8; off <<= 1) m = fmaxf(m, __shfl_xor(m, off));
    float s = 0.f;
    #pragma unroll
    for (int i = 0; i < 5; ++i) { acc[i] = expf(acc[i] - m); s += acc[i]; }
    for (int off = 1; off < 8; off <<= 1) s += __shfl_xor(s, off);
    float inv = 1.0f / s;

    int gr = row0 + r;
    if (gr < N) {
        #pragma unroll
        for (int i = 0; i < 5; ++i) out[(size_t)gr * 40 + c0 + i] = acc[i] * inv;
    }
}

// ---- launcher -----------------------------------------------------------

extern "C" void kernel_launch(void* const* d_in, const int* in_sizes, int n_in,
                              void* d_out, int out_size, void* d_ws, size_t ws_size,
                              hipStream_t stream) {
    const float* x   = (const float*)d_in[0];
    const int*   e   = (const int*)d_in[1];
    const float* W1l = (const float*)d_in[2];
    const float* b1  = (const float*)d_in[3];
    const float* W1r = (const float*)d_in[4];
    const float* W2l = (const float*)d_in[5];
    const float* b2  = (const float*)d_in[6];
    const float* W2r = (const float*)d_in[7];
    const float* W3l = (const float*)d_in[8];
    const float* b3  = (const float*)d_in[9];
    const float* W3r = (const float*)d_in[10];
    const float* Wfc = (const float*)d_in[11];
    const float* bfc = (const float*)d_in[12];
    float* out = (float*)d_out;

    const int N = NN;
    const int E = in_sizes[1] / 2;

    unsigned char* p = (unsigned char*)d_ws;
    unsigned short* xb   = (unsigned short*)p; p += (size_t)N * D * 2;
    unsigned short* h1b  = (unsigned short*)p; p += (size_t)N * D * 2;
    unsigned short* h2b  = (unsigned short*)p; p += (size_t)N * D * 2;
    unsigned short* aggb = (unsigned short*)p; p += (size_t)N * D * 2;
    unsigned short* w1lp = (unsigned short*)p; p += 16384 * 2;
    unsigned short* w1rp = (unsigned short*)p; p += 16384 * 2;
    unsigned short* w2lp = (unsigned short*)p; p += 16384 * 2;
    unsigned short* w2rp = (unsigned short*)p; p += 16384 * 2;
    unsigned short* w3lp = (unsigned short*)p; p += 16384 * 2;
    unsigned short* w3rp = (unsigned short*)p; p += 16384 * 2;
    float* inv_cnt = (float*)p; p += (size_t)N * 4;
    int* row_ptr = (int*)p; p += (size_t)(N + 4) * 4;
    int* cnt  = (int*)p; p += (size_t)N * 4;
    int* fill = (int*)p; p += (size_t)N * 4;
    int* bsum = (int*)p; p += 64 * 4;
    unsigned short* csr_src = (unsigned short*)p;
    float* h3f = (float*)xb;   // overlays xb+h1b (dead by layer 3)

    hipMemsetAsync(cnt, 0, sizeof(int) * N, stream);

    f32_to_bf16_kernel<<<(N * D / 4 + 255) / 256, 256, 0, stream>>>(x, xb, N * D / 4);
    pack_w_kernel<<<64, 256, 0, stream>>>(W1l, w1lp);
    pack_w_kernel<<<64, 256, 0, stream>>>(W1r, w1rp);
    pack_w_kernel<<<64, 256, 0, stream>>>(W2l, w2lp);
    pack_w_kernel<<<64, 256, 0, stream>>>(W2r, w2rp);
    pack_w_kernel<<<64, 256, 0, stream>>>(W3l, w3lp);
    pack_w_kernel<<<64, 256, 0, stream>>>(W3r, w3rp);

    count_kernel<<<(E / 4 + 255) / 256, 256, 0, stream>>>(e, E, cnt);
    scan_blocks_kernel<<<NB, 256, 0, stream>>>(cnt, row_ptr, bsum, N);
    scan_bsums_kernel<<<1, 64, 0, stream>>>(bsum, NB);
    scan_add_kernel<<<NB, 256, 0, stream>>>(cnt, row_ptr, bsum, inv_cnt, fill, N, E);
    scatter_kernel<<<(E / 4 + 255) / 256, 256, 0, stream>>>(e, E, fill, csr_src);

    int aggBlocks = (N * 32 + 255) / 256;
    int sageBlocks = (N + 63) / 64;
    int fcBlocks = (N + 31) / 32;

    aggregate_kernel<<<aggBlocks, 256, 0, stream>>>(xb, row_ptr, csr_src, inv_cnt, aggb, N);
    sage_mfma_kernel<<<sageBlocks, 256, 0, stream>>>(aggb, xb, w1lp, w1rp, b1,
                                                     h1b, nullptr, 1, N);

    aggregate_kernel<<<aggBlocks, 256, 0, stream>>>(h1b, row_ptr, csr_src, inv_cnt, aggb, N);
    sage_mfma_kernel<<<sageBlocks, 256, 0, stream>>>(aggb, h1b, w2lp, w2rp, b2,
                                                     h2b, nullptr, 1, N);

    aggregate_kernel<<<aggBlocks, 256, 0, stream>>>(h2b, row_ptr, csr_src, inv_cnt, aggb, N);
    sage_mfma_kernel<<<sageBlocks, 256, 0, stream>>>(aggb, h2b, w3lp, w3rp, b3,
                                                     nullptr, h3f, 0, N);

    fc_softmax_kernel<<<fcBlocks, 256, 0, stream>>>(h3f, Wfc, bfc, out, N);
}

// Round 14
// 222.282 us; speedup vs baseline: 2.7806x; 1.2325x over previous
//
#include <hip/hip_runtime.h>
#include <math.h>

#define NN 50000
#define D 128
#define NB 49      // scan blocks over N: ceil(50000/1024)
#define NBUK 256   // dst buckets (dst>>8), covers 65536 >= N
#define EPB 4096   // edges per block in bucket passes

typedef __attribute__((ext_vector_type(8))) short bf16x8;
typedef __attribute__((ext_vector_type(4))) float f32x4;

__device__ __forceinline__ float bf2f(unsigned short u) {
    union { unsigned int i; float f; } c;
    c.i = ((unsigned int)u) << 16;
    return c.f;
}
__device__ __forceinline__ unsigned short f2bf(float f) {
    union { float f; unsigned int i; } c;
    c.f = f;
    unsigned int u = c.i;
    return (unsigned short)((u + 0x7FFFu + ((u >> 16) & 1u)) >> 16);
}

// ---- fp32 -> bf16 bulk convert ------------------------------------------

__global__ __launch_bounds__(256) void f32_to_bf16_kernel(const float* __restrict__ src,
                                                          unsigned short* __restrict__ dst,
                                                          int n4) {
    int i = blockIdx.x * 256 + threadIdx.x;
    if (i < n4) {
        float4 v = ((const float4*)src)[i];
        ushort4 o;
        o.x = f2bf(v.x); o.y = f2bf(v.y); o.z = f2bf(v.z); o.w = f2bf(v.w);
        ((ushort4*)dst)[i] = o;
    }
}

// ---- pack all 6 weights [128][128] fp32 -> MFMA B-frag bf16 -------------
// frag (ks,n): lane l elem e holds W[ks*32 + (l>>4)*8 + e][n*16 + (l&15)]

__global__ __launch_bounds__(256) void pack_all_kernel(const float* __restrict__ W0,
                                                       const float* __restrict__ W1,
                                                       const float* __restrict__ W2,
                                                       const float* __restrict__ W3,
                                                       const float* __restrict__ W4,
                                                       const float* __restrict__ W5,
                                                       unsigned short* __restrict__ P) {
    int i = blockIdx.x * 256 + threadIdx.x;   // 0..98303
    int w = i >> 14, j = i & 16383;
    const float* W = (w == 0) ? W0 : (w == 1) ? W1 : (w == 2) ? W2
                   : (w == 3) ? W3 : (w == 4) ? W4 : W5;
    int e = j & 7, l = (j >> 3) & 63, n = (j >> 9) & 7, ks = j >> 12;
    int k = ks * 32 + (l >> 4) * 8 + e;
    int col = n * 16 + (l & 15);
    P[i] = f2bf(W[k * D + col]);
}

// ---- bucketed CSR build -------------------------------------------------

// pass 1: per-block LDS histogram of dst>>8, one global atomic per bucket
__global__ __launch_bounds__(256) void bucket_hist_kernel(const int* __restrict__ e, int E,
                                                          int* __restrict__ bukcnt) {
    __shared__ int h[NBUK];
    int t = threadIdx.x;
    h[t] = 0;
    __syncthreads();
    int base = blockIdx.x * EPB;
    #pragma unroll
    for (int k = 0; k < 4; ++k) {
        int idx = base + k * 1024 + t * 4;
        if (idx + 4 <= E) {
            int4 d = *(const int4*)(e + E + idx);
            atomicAdd(&h[d.x >> 8], 1);
            atomicAdd(&h[d.y >> 8], 1);
            atomicAdd(&h[d.z >> 8], 1);
            atomicAdd(&h[d.w >> 8], 1);
        } else {
            for (int i = idx; i < E; ++i) atomicAdd(&h[e[E + i] >> 8], 1);
        }
    }
    __syncthreads();
    if (h[t]) atomicAdd(&bukcnt[t], h[t]);
}

// pass 2: exclusive scan of 256 bucket counts -> bukbase, bukfill
__global__ __launch_bounds__(256) void bucket_scan_kernel(const int* __restrict__ bukcnt,
                                                          int* __restrict__ bukbase,
                                                          int* __restrict__ bukfill, int E) {
    __shared__ int wsum[4], woff[4];
    int t = threadIdx.x;
    int lane = t & 63, wave = t >> 6;
    int v = bukcnt[t];
    int incl = v;
    for (int off = 1; off < 64; off <<= 1) {
        int u = __shfl_up(incl, off);
        if (lane >= off) incl += u;
    }
    if (lane == 63) wsum[wave] = incl;
    __syncthreads();
    if (t == 0) {
        int r = 0;
        #pragma unroll
        for (int w = 0; w < 4; ++w) { woff[w] = r; r += wsum[w]; }
    }
    __syncthreads();
    int excl = woff[wave] + incl - v;
    bukbase[t] = excl;
    bukfill[t] = excl;
    if (t == 255) bukbase[NBUK] = E;
}

// pass 3: scatter packed (src | dstlow<<16) into bucket regions.
// Blocks reserve per-bucket ranges -> writes are consecutive, coalesced.
__global__ __launch_bounds__(256) void bucket_scatter_kernel(const int* __restrict__ e, int E,
                                                             int* __restrict__ bukfill,
                                                             unsigned int* __restrict__ ebuk) {
    __shared__ int h[NBUK];
    __shared__ int res[NBUK];
    int t = threadIdx.x;
    h[t] = 0;
    __syncthreads();
    int base = blockIdx.x * EPB;
    int4 d[4];
    #pragma unroll
    for (int k = 0; k < 4; ++k) {
        int idx = base + k * 1024 + t * 4;
        if (idx + 4 <= E) {
            d[k] = *(const int4*)(e + E + idx);
        } else {
            d[k].x = (idx + 0 < E) ? e[E + idx + 0] : -1;
            d[k].y = (idx + 1 < E) ? e[E + idx + 1] : -1;
            d[k].z = (idx + 2 < E) ? e[E + idx + 2] : -1;
            d[k].w = (idx + 3 < E) ? e[E + idx + 3] : -1;
        }
        if (d[k].x >= 0) atomicAdd(&h[d[k].x >> 8], 1);
        if (d[k].y >= 0) atomicAdd(&h[d[k].y >> 8], 1);
        if (d[k].z >= 0) atomicAdd(&h[d[k].z >> 8], 1);
        if (d[k].w >= 0) atomicAdd(&h[d[k].w >> 8], 1);
    }
    __syncthreads();
    res[t] = h[t] ? atomicAdd(&bukfill[t], h[t]) : 0;
    h[t] = 0;
    __syncthreads();
    #pragma unroll
    for (int k = 0; k < 4; ++k) {
        int idx = base + k * 1024 + t * 4;
        int4 s;
        if (idx + 4 <= E) {
            s = *(const int4*)(e + idx);
        } else {
            s.x = (idx + 0 < E) ? e[idx + 0] : 0;
            s.y = (idx + 1 < E) ? e[idx + 1] : 0;
            s.z = (idx + 2 < E) ? e[idx + 2] : 0;
            s.w = (idx + 3 < E) ? e[idx + 3] : 0;
        }
        if (d[k].x >= 0) { int b = d[k].x >> 8; int r = atomicAdd(&h[b], 1);
            ebuk[res[b] + r] = (unsigned int)(s.x & 0xFFFF) | ((unsigned int)(d[k].x & 255) << 16); }
        if (d[k].y >= 0) { int b = d[k].y >> 8; int r = atomicAdd(&h[b], 1);
            ebuk[res[b] + r] = (unsigned int)(s.y & 0xFFFF) | ((unsigned int)(d[k].y & 255) << 16); }
        if (d[k].z >= 0) { int b = d[k].z >> 8; int r = atomicAdd(&h[b], 1);
            ebuk[res[b] + r] = (unsigned int)(s.z & 0xFFFF) | ((unsigned int)(d[k].z & 255) << 16); }
        if (d[k].w >= 0) { int b = d[k].w >> 8; int r = atomicAdd(&h[b], 1);
            ebuk[res[b] + r] = (unsigned int)(s.w & 0xFFFF) | ((unsigned int)(d[k].w & 255) << 16); }
    }
}

// pass 4: per-bucket dst histogram -> coalesced cnt writes (no memset)
__global__ __launch_bounds__(256) void cnt_hist_kernel(const unsigned int* __restrict__ ebuk,
                                                       const int* __restrict__ bukbase,
                                                       int* __restrict__ cnt, int N) {
    __shared__ int c[NBUK];
    int t = threadIdx.x, b = blockIdx.x;
    c[t] = 0;
    __syncthreads();
    int lo = bukbase[b], hi = bukbase[b + 1];
    for (int i = lo + t; i < hi; i += 256) atomicAdd(&c[ebuk[i] >> 16], 1);
    __syncthreads();
    int g = b * NBUK + t;
    if (g < N) cnt[g] = c[t];
}

// scans over N (unchanged structure)
__global__ __launch_bounds__(256) void scan_blocks_kernel(const int* __restrict__ cnt,
                                                          int* __restrict__ row_ptr,
                                                          int* __restrict__ bsum, int N) {
    __shared__ int wsum[4], woff[4];
    int t = threadIdx.x;
    int lane = t & 63, wave = t >> 6;
    int base = blockIdx.x * 1024 + t * 4;
    int4 v = make_int4(0, 0, 0, 0);
    if (base + 4 <= N) v = *(const int4*)(cnt + base);
    int s = v.x + v.y + v.z + v.w;
    int incl = s;
    for (int off = 1; off < 64; off <<= 1) {
        int u = __shfl_up(incl, off);
        if (lane >= off) incl += u;
    }
    if (lane == 63) wsum[wave] = incl;
    __syncthreads();
    if (t == 0) {
        int r = 0;
        #pragma unroll
        for (int w = 0; w < 4; ++w) { woff[w] = r; r += wsum[w]; }
    }
    __syncthreads();
    int excl = woff[wave] + incl - s;
    if (base + 4 <= N) {
        int4 rp;
        rp.x = excl;
        rp.y = rp.x + v.x;
        rp.z = rp.y + v.y;
        rp.w = rp.z + v.z;
        *(int4*)(row_ptr + base) = rp;
    }
    if (t == 255) bsum[blockIdx.x] = woff[3] + wsum[3];
}

__global__ __launch_bounds__(64) void scan_bsums_kernel(int* __restrict__ bsum, int nb) {
    int l = threadIdx.x;
    int v = (l < nb) ? bsum[l] : 0;
    int incl = v;
    for (int off = 1; off < 64; off <<= 1) {
        int u = __shfl_up(incl, off);
        if (l >= off) incl += u;
    }
    if (l < nb) bsum[l] = incl - v;
}

__global__ __launch_bounds__(256) void scan_add_kernel(const int* __restrict__ cnt,
                                                       int* __restrict__ row_ptr,
                                                       const int* __restrict__ bsum,
                                                       float* __restrict__ inv_cnt,
                                                       int N, int E) {
    int base = blockIdx.x * 1024 + threadIdx.x * 4;
    int off = bsum[blockIdx.x];
    if (base + 4 <= N) {
        int4 rp = *(int4*)(row_ptr + base);
        rp.x += off; rp.y += off; rp.z += off; rp.w += off;
        *(int4*)(row_ptr + base) = rp;
        int4 c = *(const int4*)(cnt + base);
        float4 ic;
        ic.x = 1.0f / fmaxf((float)c.x, 1.0f);
        ic.y = 1.0f / fmaxf((float)c.y, 1.0f);
        ic.z = 1.0f / fmaxf((float)c.z, 1.0f);
        ic.w = 1.0f / fmaxf((float)c.w, 1.0f);
        *(float4*)(inv_cnt + base) = ic;
    }
    if (blockIdx.x == 0 && threadIdx.x == 0) row_ptr[N] = E;
}

// pass 5: per-bucket final scatter; writes land in one contiguous region
__global__ __launch_bounds__(256) void csr_scatter_kernel(const unsigned int* __restrict__ ebuk,
                                                          const int* __restrict__ bukbase,
                                                          const int* __restrict__ row_ptr,
                                                          unsigned short* __restrict__ csr_src,
                                                          int N) {
    __shared__ int rp[NBUK];
    __shared__ int lf[NBUK];
    int t = threadIdx.x, b = blockIdx.x;
    int g = b * NBUK + t;
    rp[t] = (g < N) ? row_ptr[g] : 0;
    lf[t] = 0;
    __syncthreads();
    int lo = bukbase[b], hi = bukbase[b + 1];
    for (int i = lo + t; i < hi; i += 256) {
        unsigned int v = ebuk[i];
        int dl = v >> 16;
        int r = atomicAdd(&lf[dl], 1);
        csr_src[rp[dl] + r] = (unsigned short)(v & 0xFFFF);
    }
}

// ---- mean aggregation on bf16 rows: 32-lane group per node --------------

__device__ __forceinline__ void acc_bf4(float& x, float& y, float& z, float& w, ushort4 v) {
    x += bf2f(v.x); y += bf2f(v.y); z += bf2f(v.z); w += bf2f(v.w);
}

__global__ __launch_bounds__(256) void aggregate_kernel(const unsigned short* __restrict__ h,
                                                        const int* __restrict__ row_ptr,
                                                        const unsigned short* __restrict__ csr_src,
                                                        const float* __restrict__ inv_cnt,
                                                        unsigned short* __restrict__ agg, int N) {
    int node = (int)((blockIdx.x * blockDim.x + threadIdx.x) >> 5);
    int l = threadIdx.x & 31;
    if (node >= N) return;
    const ushort4* h4 = (const ushort4*)h;   // 32 ushort4 per row
    int beg = row_ptr[node], end = row_ptr[node + 1];
    float a0x = 0.f, a0y = 0.f, a0z = 0.f, a0w = 0.f;
    float a1x = 0.f, a1y = 0.f, a1z = 0.f, a1w = 0.f;
    for (int base = beg; base < end; base += 32) {
        int idx = 0;
        if (base + l < end) idx = csr_src[base + l];
        int n = min(32, end - base);
        int j = 0;
        for (; j + 8 <= n; j += 8) {
            int s0 = __shfl(idx, j + 0, 32);
            int s1 = __shfl(idx, j + 1, 32);
            int s2 = __shfl(idx, j + 2, 32);
            int s3 = __shfl(idx, j + 3, 32);
            int s4 = __shfl(idx, j + 4, 32);
            int s5 = __shfl(idx, j + 5, 32);
            int s6 = __shfl(idx, j + 6, 32);
            int s7 = __shfl(idx, j + 7, 32);
            ushort4 v0 = h4[(size_t)s0 * 32 + l];
            ushort4 v1 = h4[(size_t)s1 * 32 + l];
            ushort4 v2 = h4[(size_t)s2 * 32 + l];
            ushort4 v3 = h4[(size_t)s3 * 32 + l];
            ushort4 v4 = h4[(size_t)s4 * 32 + l];
            ushort4 v5 = h4[(size_t)s5 * 32 + l];
            ushort4 v6 = h4[(size_t)s6 * 32 + l];
            ushort4 v7 = h4[(size_t)s7 * 32 + l];
            acc_bf4(a0x, a0y, a0z, a0w, v0);
            acc_bf4(a1x, a1y, a1z, a1w, v1);
            acc_bf4(a0x, a0y, a0z, a0w, v2);
            acc_bf4(a1x, a1y, a1z, a1w, v3);
            acc_bf4(a0x, a0y, a0z, a0w, v4);
            acc_bf4(a1x, a1y, a1z, a1w, v5);
            acc_bf4(a0x, a0y, a0z, a0w, v6);
            acc_bf4(a1x, a1y, a1z, a1w, v7);
        }
        for (; j < n; ++j) {
            int s = __shfl(idx, j, 32);
            ushort4 v = h4[(size_t)s * 32 + l];
            acc_bf4(a0x, a0y, a0z, a0w, v);
        }
    }
    float iv = inv_cnt[node];
    ushort4 o;
    o.x = f2bf((a0x + a1x) * iv);
    o.y = f2bf((a0y + a1y) * iv);
    o.z = f2bf((a0z + a1z) * iv);
    o.w = f2bf((a0w + a1w) * iv);
    ((ushort4*)agg)[(size_t)node * 32 + l] = o;
}

// ---- MFMA dual-GEMM + bias + L2-normalize + (ReLU) ----------------------

__global__ __launch_bounds__(256) void sage_mfma_kernel(const unsigned short* __restrict__ aggb,
                                                        const unsigned short* __restrict__ xb,
                                                        const unsigned short* __restrict__ wlp,
                                                        const unsigned short* __restrict__ wrp,
                                                        const float* __restrict__ bl,
                                                        unsigned short* __restrict__ outb,
                                                        float* __restrict__ outf,
                                                        int relu, int N) {
    int t = threadIdx.x;
    int w = t >> 6;
    int l = t & 63;
    int rlo = l & 15;
    int khi = l >> 4;
    int row0 = blockIdx.x * 64 + w * 16;
    int rowA = row0 + rlo;
    bool okA = rowA < N;

    f32x4 acc[8];
    #pragma unroll
    for (int n = 0; n < 8; ++n) {
        float b = bl[n * 16 + rlo];
        acc[n] = (f32x4){b, b, b, b};
    }

    const short* Ap = (const short*)aggb + (size_t)(okA ? rowA : 0) * D + khi * 8;
    const short* Xp = (const short*)xb   + (size_t)(okA ? rowA : 0) * D + khi * 8;
    const short* WL = (const short*)wlp + l * 8;
    const short* WR = (const short*)wrp + l * 8;
    const bf16x8 Z = {0, 0, 0, 0, 0, 0, 0, 0};

    #pragma unroll 1
    for (int ks = 0; ks < 4; ++ks) {
        bf16x8 a = okA ? *(const bf16x8*)(Ap + ks * 32) : Z;
        #pragma unroll
        for (int n = 0; n < 8; ++n) {
            bf16x8 b = *(const bf16x8*)(WL + (ks * 8 + n) * 512);
            acc[n] = __builtin_amdgcn_mfma_f32_16x16x32_bf16(a, b, acc[n], 0, 0, 0);
        }
    }
    #pragma unroll 1
    for (int ks = 0; ks < 4; ++ks) {
        bf16x8 a = okA ? *(const bf16x8*)(Xp + ks * 32) : Z;
        #pragma unroll
        for (int n = 0; n < 8; ++n) {
            bf16x8 b = *(const bf16x8*)(WR + (ks * 8 + n) * 512);
            acc[n] = __builtin_amdgcn_mfma_f32_16x16x32_bf16(a, b, acc[n], 0, 0, 0);
        }
    }

    #pragma unroll
    for (int r = 0; r < 4; ++r) {
        float s = 0.f;
        #pragma unroll
        for (int n = 0; n < 8; ++n) s += acc[n][r] * acc[n][r];
        s += __shfl_xor(s, 1);
        s += __shfl_xor(s, 2);
        s += __shfl_xor(s, 4);
        s += __shfl_xor(s, 8);
        float inv = 1.0f / fmaxf(sqrtf(s), 1e-12f);
        int gr = row0 + khi * 4 + r;
        if (gr < N) {
            if (outb) {
                #pragma unroll
                for (int n = 0; n < 8; ++n) {
                    float v = acc[n][r] * inv;
                    if (relu) v = fmaxf(v, 0.f);
                    outb[(size_t)gr * D + n * 16 + rlo] = f2bf(v);
                }
            } else {
                #pragma unroll
                for (int n = 0; n < 8; ++n) {
                    float v = acc[n][r] * inv;
                    outf[(size_t)gr * D + n * 16 + rlo] = v;
                }
            }
        }
    }
}

// ---- final FC + softmax: LDS-tiled, 32 rows/block, 8 threads/row --------

__global__ __launch_bounds__(256, 4) void fc_softmax_kernel(const float* __restrict__ h,
                                                            const float* __restrict__ Wfc,
                                                            const float* __restrict__ bfc,
                                                            float* __restrict__ out, int N) {
    __shared__ float sH[32 * 132];
    __shared__ float sW[128 * 40];
    __shared__ float sB[40];
    int t = threadIdx.x;
    int row0 = blockIdx.x * 32;

    const float4* W4 = (const float4*)Wfc;
    float4* sW4 = (float4*)sW;
    for (int i = t; i < 1280; i += 256) sW4[i] = W4[i];
    if (t < 40) sB[t] = bfc[t];

    const float4* h4 = (const float4*)h;
    for (int i = t; i < 32 * 32; i += 256) {
        int r = i >> 5, c = i & 31;
        int gr = row0 + r;
        float4 v = make_float4(0.f, 0.f, 0.f, 0.f);
        if (gr < N) v = h4[(size_t)gr * 32 + c];
        *(float4*)(sH + r * 132 + c * 4) = v;
    }
    __syncthreads();

    int r = t >> 3, sub = t & 7;
    int c0 = sub * 5;
    float acc[5];
    #pragma unroll
    for (int i = 0; i < 5; ++i) acc[i] = sB[c0 + i];

    const float* hr = sH + r * 132;
    for (int k = 0; k < 128; ++k) {
        float hv = hr[k];
        const float* wk = sW + k * 40 + c0;
        #pragma unroll
        for (int i = 0; i < 5; ++i) acc[i] += hv * wk[i];
    }

    float m = acc[0];
    #pragma unroll
    for (int i = 1; i < 5; ++i) m = fmaxf(m, acc[i]);
    for (int off = 1; off < 8; off <<= 1) m = fmaxf(m, __shfl_xor(m, off));
    float s = 0.f;
    #pragma unroll
    for (int i = 0; i < 5; ++i) { acc[i] = expf(acc[i] - m); s += acc[i]; }
    for (int off = 1; off < 8; off <<= 1) s += __shfl_xor(s, off);
    float inv = 1.0f / s;

    int gr = row0 + r;
    if (gr < N) {
        #pragma unroll
        for (int i = 0; i < 5; ++i) out[(size_t)gr * 40 + c0 + i] = acc[i] * inv;
    }
}

// ---- launcher -----------------------------------------------------------

extern "C" void kernel_launch(void* const* d_in, const int* in_sizes, int n_in,
                              void* d_out, int out_size, void* d_ws, size_t ws_size,
                              hipStream_t stream) {
    const float* x   = (const float*)d_in[0];
    const int*   e   = (const int*)d_in[1];
    const float* W1l = (const float*)d_in[2];
    const float* b1  = (const float*)d_in[3];
    const float* W1r = (const float*)d_in[4];
    const float* W2l = (const float*)d_in[5];
    const float* b2  = (const float*)d_in[6];
    const float* W2r = (const float*)d_in[7];
    const float* W3l = (const float*)d_in[8];
    const float* b3  = (const float*)d_in[9];
    const float* W3r = (const float*)d_in[10];
    const float* Wfc = (const float*)d_in[11];
    const float* bfc = (const float*)d_in[12];
    float* out = (float*)d_out;

    const int N = NN;
    const int E = in_sizes[1] / 2;

    unsigned char* p = (unsigned char*)d_ws;
    unsigned short* xb   = (unsigned short*)p; p += (size_t)N * D * 2;
    unsigned short* h1b  = (unsigned short*)p; p += (size_t)N * D * 2;
    unsigned short* h2b  = (unsigned short*)p; p += (size_t)N * D * 2;
    unsigned short* aggb = (unsigned short*)p; p += (size_t)N * D * 2;
    unsigned short* wpk  = (unsigned short*)p; p += 6 * 16384 * 2;   // 6 packed weights
    float* inv_cnt = (float*)p; p += (size_t)N * 4;
    int* row_ptr = (int*)p; p += (size_t)(N + 4) * 4;
    int* cnt     = (int*)p; p += (size_t)N * 4;
    int* bukcnt  = (int*)p; p += NBUK * 4;
    int* bukbase = (int*)p; p += (NBUK + 4) * 4;
    int* bukfill = (int*)p; p += NBUK * 4;
    int* bsum    = (int*)p; p += 64 * 4;
    unsigned int* ebuk = (unsigned int*)p; p += (size_t)E * 4;
    unsigned short* csr_src = (unsigned short*)p;
    float* h3f = (float*)xb;   // overlays xb+h1b (dead by layer 3)

    unsigned short* w1lp = wpk;
    unsigned short* w1rp = wpk + 16384;
    unsigned short* w2lp = wpk + 2 * 16384;
    unsigned short* w2rp = wpk + 3 * 16384;
    unsigned short* w3lp = wpk + 4 * 16384;
    unsigned short* w3rp = wpk + 5 * 16384;

    hipMemsetAsync(bukcnt, 0, sizeof(int) * NBUK, stream);

    f32_to_bf16_kernel<<<(N * D / 4 + 255) / 256, 256, 0, stream>>>(x, xb, N * D / 4);
    pack_all_kernel<<<384, 256, 0, stream>>>(W1l, W1r, W2l, W2r, W3l, W3r, wpk);

    int EB = (E + EPB - 1) / EPB;
    bucket_hist_kernel<<<EB, 256, 0, stream>>>(e, E, bukcnt);
    bucket_scan_kernel<<<1, 256, 0, stream>>>(bukcnt, bukbase, bukfill, E);
    bucket_scatter_kernel<<<EB, 256, 0, stream>>>(e, E, bukfill, ebuk);
    cnt_hist_kernel<<<NBUK, 256, 0, stream>>>(ebuk, bukbase, cnt, N);
    scan_blocks_kernel<<<NB, 256, 0, stream>>>(cnt, row_ptr, bsum, N);
    scan_bsums_kernel<<<1, 64, 0, stream>>>(bsum, NB);
    scan_add_kernel<<<NB, 256, 0, stream>>>(cnt, row_ptr, bsum, inv_cnt, N, E);
    csr_scatter_kernel<<<NBUK, 256, 0, stream>>>(ebuk, bukbase, row_ptr, csr_src, N);

    int aggBlocks = (N * 32 + 255) / 256;
    int sageBlocks = (N + 63) / 64;
    int fcBlocks = (N + 31) / 32;

    aggregate_kernel<<<aggBlocks, 256, 0, stream>>>(xb, row_ptr, csr_src, inv_cnt, aggb, N);
    sage_mfma_kernel<<<sageBlocks, 256, 0, stream>>>(aggb, xb, w1lp, w1rp, b1,
                                                     h1b, nullptr, 1, N);

    aggregate_kernel<<<aggBlocks, 256, 0, stream>>>(h1b, row_ptr, csr_src, inv_cnt, aggb, N);
    sage_mfma_kernel<<<sageBlocks, 256, 0, stream>>>(aggb, h1b, w2lp, w2rp, b2,
                                                     h2b, nullptr, 1, N);

    aggregate_kernel<<<aggBlocks, 256, 0, stream>>>(h2b, row_ptr, csr_src, inv_cnt, aggb, N);
    sage_mfma_kernel<<<sageBlocks, 256, 0, stream>>>(aggb, h2b, w3lp, w3rp, b3,
                                                     nullptr, h3f, 0, N);

    fc_softmax_kernel<<<fcBlocks, 256, 0, stream>>>(h3f, Wfc, bfc, out, N);
}

// Round 15
// 203.972 us; speedup vs baseline: 3.0302x; 1.0898x over previous
//
#include <hip/hip_runtime.h>
#include <math.h>

#define NN 50000
#define D 128
#define NB 49      // scan blocks over N: ceil(50000/1024)
#define NBUK 256   // dst buckets (dst>>8), covers 65536 >= N
#define EPB 4096   // edges per block in bucket passes

typedef __attribute__((ext_vector_type(8))) short bf16x8;
typedef __attribute__((ext_vector_type(4))) float f32x4;
typedef __attribute__((ext_vector_type(2))) float f32x2;

__device__ __forceinline__ float bf2f(unsigned short u) {
    union { unsigned int i; float f; } c;
    c.i = ((unsigned int)u) << 16;
    return c.f;
}
__device__ __forceinline__ unsigned short f2bf(float f) {
    union { float f; unsigned int i; } c;
    c.f = f;
    unsigned int u = c.i;
    return (unsigned short)((u + 0x7FFFu + ((u >> 16) & 1u)) >> 16);
}
__device__ __forceinline__ unsigned char f2f8(float v) {
    return (unsigned char)(__builtin_amdgcn_cvt_pk_fp8_f32(v, v, 0, false) & 0xFF);
}

// ---- fp32 -> bf16 + fp8 bulk convert ------------------------------------

__global__ __launch_bounds__(256) void f32_cvt_kernel(const float* __restrict__ src,
                                                      unsigned short* __restrict__ dstb,
                                                      unsigned int* __restrict__ dst8,
                                                      int n4) {
    int i = blockIdx.x * 256 + threadIdx.x;
    if (i < n4) {
        float4 v = ((const float4*)src)[i];
        ushort4 o;
        o.x = f2bf(v.x); o.y = f2bf(v.y); o.z = f2bf(v.z); o.w = f2bf(v.w);
        ((ushort4*)dstb)[i] = o;
        unsigned int p01 = __builtin_amdgcn_cvt_pk_fp8_f32(v.x, v.y, 0, false);
        unsigned int p23 = __builtin_amdgcn_cvt_pk_fp8_f32(v.z, v.w, 0, false);
        dst8[i] = (p01 & 0xFFFFu) | (p23 << 16);
    }
}

// ---- pack all 6 weights [128][128] fp32 -> MFMA B-frag bf16 -------------

__global__ __launch_bounds__(256) void pack_all_kernel(const float* __restrict__ W0,
                                                       const float* __restrict__ W1,
                                                       const float* __restrict__ W2,
                                                       const float* __restrict__ W3,
                                                       const float* __restrict__ W4,
                                                       const float* __restrict__ W5,
                                                       unsigned short* __restrict__ P) {
    int i = blockIdx.x * 256 + threadIdx.x;   // 0..98303
    int w = i >> 14, j = i & 16383;
    const float* W = (w == 0) ? W0 : (w == 1) ? W1 : (w == 2) ? W2
                   : (w == 3) ? W3 : (w == 4) ? W4 : W5;
    int e = j & 7, l = (j >> 3) & 63, n = (j >> 9) & 7, ks = j >> 12;
    int k = ks * 32 + (l >> 4) * 8 + e;
    int col = n * 16 + (l & 15);
    P[i] = f2bf(W[k * D + col]);
}

// ---- bucketed CSR build -------------------------------------------------

__global__ __launch_bounds__(256) void bucket_hist_kernel(const int* __restrict__ e, int E,
                                                          int* __restrict__ bukcnt) {
    __shared__ int h[NBUK];
    int t = threadIdx.x;
    h[t] = 0;
    __syncthreads();
    int base = blockIdx.x * EPB;
    #pragma unroll
    for (int k = 0; k < 4; ++k) {
        int idx = base + k * 1024 + t * 4;
        if (idx + 4 <= E) {
            int4 d = *(const int4*)(e + E + idx);
            atomicAdd(&h[d.x >> 8], 1);
            atomicAdd(&h[d.y >> 8], 1);
            atomicAdd(&h[d.z >> 8], 1);
            atomicAdd(&h[d.w >> 8], 1);
        } else {
            for (int i = idx; i < E; ++i) atomicAdd(&h[e[E + i] >> 8], 1);
        }
    }
    __syncthreads();
    if (h[t]) atomicAdd(&bukcnt[t], h[t]);
}

__global__ __launch_bounds__(256) void bucket_scan_kernel(const int* __restrict__ bukcnt,
                                                          int* __restrict__ bukbase,
                                                          int* __restrict__ bukfill, int E) {
    __shared__ int wsum[4], woff[4];
    int t = threadIdx.x;
    int lane = t & 63, wave = t >> 6;
    int v = bukcnt[t];
    int incl = v;
    for (int off = 1; off < 64; off <<= 1) {
        int u = __shfl_up(incl, off);
        if (lane >= off) incl += u;
    }
    if (lane == 63) wsum[wave] = incl;
    __syncthreads();
    if (t == 0) {
        int r = 0;
        #pragma unroll
        for (int w = 0; w < 4; ++w) { woff[w] = r; r += wsum[w]; }
    }
    __syncthreads();
    int excl = woff[wave] + incl - v;
    bukbase[t] = excl;
    bukfill[t] = excl;
    if (t == 255) bukbase[NBUK] = E;
}

__global__ __launch_bounds__(256) void bucket_scatter_kernel(const int* __restrict__ e, int E,
                                                             int* __restrict__ bukfill,
                                                             unsigned int* __restrict__ ebuk) {
    __shared__ int h[NBUK];
    __shared__ int res[NBUK];
    int t = threadIdx.x;
    h[t] = 0;
    __syncthreads();
    int base = blockIdx.x * EPB;
    int4 d[4];
    #pragma unroll
    for (int k = 0; k < 4; ++k) {
        int idx = base + k * 1024 + t * 4;
        if (idx + 4 <= E) {
            d[k] = *(const int4*)(e + E + idx);
        } else {
            d[k].x = (idx + 0 < E) ? e[E + idx + 0] : -1;
            d[k].y = (idx + 1 < E) ? e[E + idx + 1] : -1;
            d[k].z = (idx + 2 < E) ? e[E + idx + 2] : -1;
            d[k].w = (idx + 3 < E) ? e[E + idx + 3] : -1;
        }
        if (d[k].x >= 0) atomicAdd(&h[d[k].x >> 8], 1);
        if (d[k].y >= 0) atomicAdd(&h[d[k].y >> 8], 1);
        if (d[k].z >= 0) atomicAdd(&h[d[k].z >> 8], 1);
        if (d[k].w >= 0) atomicAdd(&h[d[k].w >> 8], 1);
    }
    __syncthreads();
    res[t] = h[t] ? atomicAdd(&bukfill[t], h[t]) : 0;
    h[t] = 0;
    __syncthreads();
    #pragma unroll
    for (int k = 0; k < 4; ++k) {
        int idx = base + k * 1024 + t * 4;
        int4 s;
        if (idx + 4 <= E) {
            s = *(const int4*)(e + idx);
        } else {
            s.x = (idx + 0 < E) ? e[idx + 0] : 0;
            s.y = (idx + 1 < E) ? e[idx + 1] : 0;
            s.z = (idx + 2 < E) ? e[idx + 2] : 0;
            s.w = (idx + 3 < E) ? e[idx + 3] : 0;
        }
        if (d[k].x >= 0) { int b = d[k].x >> 8; int r = atomicAdd(&h[b], 1);
            ebuk[res[b] + r] = (unsigned int)(s.x & 0xFFFF) | ((unsigned int)(d[k].x & 255) << 16); }
        if (d[k].y >= 0) { int b = d[k].y >> 8; int r = atomicAdd(&h[b], 1);
            ebuk[res[b] + r] = (unsigned int)(s.y & 0xFFFF) | ((unsigned int)(d[k].y & 255) << 16); }
        if (d[k].z >= 0) { int b = d[k].z >> 8; int r = atomicAdd(&h[b], 1);
            ebuk[res[b] + r] = (unsigned int)(s.z & 0xFFFF) | ((unsigned int)(d[k].z & 255) << 16); }
        if (d[k].w >= 0) { int b = d[k].w >> 8; int r = atomicAdd(&h[b], 1);
            ebuk[res[b] + r] = (unsigned int)(s.w & 0xFFFF) | ((unsigned int)(d[k].w & 255) << 16); }
    }
}

__global__ __launch_bounds__(256) void cnt_hist_kernel(const unsigned int* __restrict__ ebuk,
                                                       const int* __restrict__ bukbase,
                                                       int* __restrict__ cnt, int N) {
    __shared__ int c[NBUK];
    int t = threadIdx.x, b = blockIdx.x;
    c[t] = 0;
    __syncthreads();
    int lo = bukbase[b], hi = bukbase[b + 1];
    for (int i = lo + t; i < hi; i += 256) atomicAdd(&c[ebuk[i] >> 16], 1);
    __syncthreads();
    int g = b * NBUK + t;
    if (g < N) cnt[g] = c[t];
}

__global__ __launch_bounds__(256) void scan_blocks_kernel(const int* __restrict__ cnt,
                                                          int* __restrict__ row_ptr,
                                                          int* __restrict__ bsum, int N) {
    __shared__ int wsum[4], woff[4];
    int t = threadIdx.x;
    int lane = t & 63, wave = t >> 6;
    int base = blockIdx.x * 1024 + t * 4;
    int4 v = make_int4(0, 0, 0, 0);
    if (base + 4 <= N) v = *(const int4*)(cnt + base);
    int s = v.x + v.y + v.z + v.w;
    int incl = s;
    for (int off = 1; off < 64; off <<= 1) {
        int u = __shfl_up(incl, off);
        if (lane >= off) incl += u;
    }
    if (lane == 63) wsum[wave] = incl;
    __syncthreads();
    if (t == 0) {
        int r = 0;
        #pragma unroll
        for (int w = 0; w < 4; ++w) { woff[w] = r; r += wsum[w]; }
    }
    __syncthreads();
    int excl = woff[wave] + incl - s;
    if (base + 4 <= N) {
        int4 rp;
        rp.x = excl;
        rp.y = rp.x + v.x;
        rp.z = rp.y + v.y;
        rp.w = rp.z + v.z;
        *(int4*)(row_ptr + base) = rp;
    }
    if (t == 255) bsum[blockIdx.x] = woff[3] + wsum[3];
}

__global__ __launch_bounds__(64) void scan_bsums_kernel(int* __restrict__ bsum, int nb) {
    int l = threadIdx.x;
    int v = (l < nb) ? bsum[l] : 0;
    int incl = v;
    for (int off = 1; off < 64; off <<= 1) {
        int u = __shfl_up(incl, off);
        if (l >= off) incl += u;
    }
    if (l < nb) bsum[l] = incl - v;
}

__global__ __launch_bounds__(256) void scan_add_kernel(const int* __restrict__ cnt,
                                                       int* __restrict__ row_ptr,
                                                       const int* __restrict__ bsum,
                                                       float* __restrict__ inv_cnt,
                                                       int N, int E) {
    int base = blockIdx.x * 1024 + threadIdx.x * 4;
    int off = bsum[blockIdx.x];
    if (base + 4 <= N) {
        int4 rp = *(int4*)(row_ptr + base);
        rp.x += off; rp.y += off; rp.z += off; rp.w += off;
        *(int4*)(row_ptr + base) = rp;
        int4 c = *(const int4*)(cnt + base);
        float4 ic;
        ic.x = 1.0f / fmaxf((float)c.x, 1.0f);
        ic.y = 1.0f / fmaxf((float)c.y, 1.0f);
        ic.z = 1.0f / fmaxf((float)c.z, 1.0f);
        ic.w = 1.0f / fmaxf((float)c.w, 1.0f);
        *(float4*)(inv_cnt + base) = ic;
    }
    if (blockIdx.x == 0 && threadIdx.x == 0) row_ptr[N] = E;
}

__global__ __launch_bounds__(256) void csr_scatter_kernel(const unsigned int* __restrict__ ebuk,
                                                          const int* __restrict__ bukbase,
                                                          const int* __restrict__ row_ptr,
                                                          unsigned short* __restrict__ csr_src,
                                                          int N) {
    __shared__ int rp[NBUK];
    __shared__ int lf[NBUK];
    int t = threadIdx.x, b = blockIdx.x;
    int g = b * NBUK + t;
    rp[t] = (g < N) ? row_ptr[g] : 0;
    lf[t] = 0;
    __syncthreads();
    int lo = bukbase[b], hi = bukbase[b + 1];
    for (int i = lo + t; i < hi; i += 256) {
        unsigned int v = ebuk[i];
        int dl = v >> 16;
        int r = atomicAdd(&lf[dl], 1);
        csr_src[rp[dl] + r] = (unsigned short)(v & 0xFFFF);
    }
}

// ---- mean aggregation over fp8 rows: 32-lane group per node -------------
// rows are 128 B fp8; lane loads uint (4 fp8 = elems [4l,4l+4)); decode via
// v_cvt_pk_f32_fp8; fp32 accumulate; bf16 agg output (elems [4l,4l+4)).

__device__ __forceinline__ void acc_f8(float& x, float& y, float& z, float& w,
                                       unsigned int v) {
    f32x2 lo = __builtin_amdgcn_cvt_pk_f32_fp8(v, false);
    f32x2 hi = __builtin_amdgcn_cvt_pk_f32_fp8(v, true);
    x += lo.x; y += lo.y; z += hi.x; w += hi.y;
}

__global__ __launch_bounds__(256) void aggregate_kernel(const unsigned int* __restrict__ h8,
                                                        const int* __restrict__ row_ptr,
                                                        const unsigned short* __restrict__ csr_src,
                                                        const float* __restrict__ inv_cnt,
                                                        unsigned short* __restrict__ agg, int N) {
    int node = (int)((blockIdx.x * blockDim.x + threadIdx.x) >> 5);
    int l = threadIdx.x & 31;
    if (node >= N) return;
    int beg = row_ptr[node], end = row_ptr[node + 1];
    float a0x = 0.f, a0y = 0.f, a0z = 0.f, a0w = 0.f;
    float a1x = 0.f, a1y = 0.f, a1z = 0.f, a1w = 0.f;
    for (int base = beg; base < end; base += 32) {
        int idx = 0;
        if (base + l < end) idx = csr_src[base + l];
        int n = min(32, end - base);
        int j = 0;
        for (; j + 8 <= n; j += 8) {
            int s0 = __shfl(idx, j + 0, 32);
            int s1 = __shfl(idx, j + 1, 32);
            int s2 = __shfl(idx, j + 2, 32);
            int s3 = __shfl(idx, j + 3, 32);
            int s4 = __shfl(idx, j + 4, 32);
            int s5 = __shfl(idx, j + 5, 32);
            int s6 = __shfl(idx, j + 6, 32);
            int s7 = __shfl(idx, j + 7, 32);
            unsigned int v0 = h8[(size_t)s0 * 32 + l];
            unsigned int v1 = h8[(size_t)s1 * 32 + l];
            unsigned int v2 = h8[(size_t)s2 * 32 + l];
            unsigned int v3 = h8[(size_t)s3 * 32 + l];
            unsigned int v4 = h8[(size_t)s4 * 32 + l];
            unsigned int v5 = h8[(size_t)s5 * 32 + l];
            unsigned int v6 = h8[(size_t)s6 * 32 + l];
            unsigned int v7 = h8[(size_t)s7 * 32 + l];
            acc_f8(a0x, a0y, a0z, a0w, v0);
            acc_f8(a1x, a1y, a1z, a1w, v1);
            acc_f8(a0x, a0y, a0z, a0w, v2);
            acc_f8(a1x, a1y, a1z, a1w, v3);
            acc_f8(a0x, a0y, a0z, a0w, v4);
            acc_f8(a1x, a1y, a1z, a1w, v5);
            acc_f8(a0x, a0y, a0z, a0w, v6);
            acc_f8(a1x, a1y, a1z, a1w, v7);
        }
        for (; j < n; ++j) {
            int s = __shfl(idx, j, 32);
            acc_f8(a0x, a0y, a0z, a0w, h8[(size_t)s * 32 + l]);
        }
    }
    float iv = inv_cnt[node];
    ushort4 o;
    o.x = f2bf((a0x + a1x) * iv);
    o.y = f2bf((a0y + a1y) * iv);
    o.z = f2bf((a0z + a1z) * iv);
    o.w = f2bf((a0w + a1w) * iv);
    ((ushort4*)agg)[(size_t)node * 32 + l] = o;
}

// ---- MFMA dual-GEMM + bias + L2-normalize + (ReLU) ----------------------
// Outputs: bf16 h (x-path of next layer) + fp8 h (gather of next layer),
// or fp32 (final layer). C/D layout (m89): col=lane&15, row=(lane>>4)*4+reg.

__global__ __launch_bounds__(256) void sage_mfma_kernel(const unsigned short* __restrict__ aggb,
                                                        const unsigned short* __restrict__ xb,
                                                        const unsigned short* __restrict__ wlp,
                                                        const unsigned short* __restrict__ wrp,
                                                        const float* __restrict__ bl,
                                                        unsigned short* __restrict__ outb,
                                                        unsigned char* __restrict__ out8,
                                                        float* __restrict__ outf,
                                                        int relu, int N) {
    int t = threadIdx.x;
    int w = t >> 6;
    int l = t & 63;
    int rlo = l & 15;
    int khi = l >> 4;
    int row0 = blockIdx.x * 64 + w * 16;
    int rowA = row0 + rlo;
    bool okA = rowA < N;

    f32x4 acc[8];
    #pragma unroll
    for (int n = 0; n < 8; ++n) {
        float b = bl[n * 16 + rlo];
        acc[n] = (f32x4){b, b, b, b};
    }

    const short* Ap = (const short*)aggb + (size_t)(okA ? rowA : 0) * D + khi * 8;
    const short* Xp = (const short*)xb   + (size_t)(okA ? rowA : 0) * D + khi * 8;
    const short* WL = (const short*)wlp + l * 8;
    const short* WR = (const short*)wrp + l * 8;
    const bf16x8 Z = {0, 0, 0, 0, 0, 0, 0, 0};

    #pragma unroll 1
    for (int ks = 0; ks < 4; ++ks) {
        bf16x8 a = okA ? *(const bf16x8*)(Ap + ks * 32) : Z;
        #pragma unroll
        for (int n = 0; n < 8; ++n) {
            bf16x8 b = *(const bf16x8*)(WL + (ks * 8 + n) * 512);
            acc[n] = __builtin_amdgcn_mfma_f32_16x16x32_bf16(a, b, acc[n], 0, 0, 0);
        }
    }
    #pragma unroll 1
    for (int ks = 0; ks < 4; ++ks) {
        bf16x8 a = okA ? *(const bf16x8*)(Xp + ks * 32) : Z;
        #pragma unroll
        for (int n = 0; n < 8; ++n) {
            bf16x8 b = *(const bf16x8*)(WR + (ks * 8 + n) * 512);
            acc[n] = __builtin_amdgcn_mfma_f32_16x16x32_bf16(a, b, acc[n], 0, 0, 0);
        }
    }

    #pragma unroll
    for (int r = 0; r < 4; ++r) {
        float s = 0.f;
        #pragma unroll
        for (int n = 0; n < 8; ++n) s += acc[n][r] * acc[n][r];
        s += __shfl_xor(s, 1);
        s += __shfl_xor(s, 2);
        s += __shfl_xor(s, 4);
        s += __shfl_xor(s, 8);
        float inv = 1.0f / fmaxf(sqrtf(s), 1e-12f);
        int gr = row0 + khi * 4 + r;
        if (gr < N) {
            if (outb) {
                #pragma unroll
                for (int n = 0; n < 8; ++n) {
                    float v = acc[n][r] * inv;
                    if (relu) v = fmaxf(v, 0.f);
                    outb[(size_t)gr * D + n * 16 + rlo] = f2bf(v);
                    out8[(size_t)gr * D + n * 16 + rlo] = f2f8(v);
                }
            } else {
                #pragma unroll
                for (int n = 0; n < 8; ++n) {
                    float v = acc[n][r] * inv;
                    outf[(size_t)gr * D + n * 16 + rlo] = v;
                }
            }
        }
    }
}

// ---- final FC + softmax: LDS-tiled, 32 rows/block, 8 threads/row --------

__global__ __launch_bounds__(256, 4) void fc_softmax_kernel(const float* __restrict__ h,
                                                            const float* __restrict__ Wfc,
                                                            const float* __restrict__ bfc,
                                                            float* __restrict__ out, int N) {
    __shared__ float sH[32 * 132];
    __shared__ float sW[128 * 40];
    __shared__ float sB[40];
    int t = threadIdx.x;
    int row0 = blockIdx.x * 32;

    const float4* W4 = (const float4*)Wfc;
    float4* sW4 = (float4*)sW;
    for (int i = t; i < 1280; i += 256) sW4[i] = W4[i];
    if (t < 40) sB[t] = bfc[t];

    const float4* h4 = (const float4*)h;
    for (int i = t; i < 32 * 32; i += 256) {
        int r = i >> 5, c = i & 31;
        int gr = row0 + r;
        float4 v = make_float4(0.f, 0.f, 0.f, 0.f);
        if (gr < N) v = h4[(size_t)gr * 32 + c];
        *(float4*)(sH + r * 132 + c * 4) = v;
    }
    __syncthreads();

    int r = t >> 3, sub = t & 7;
    int c0 = sub * 5;
    float acc[5];
    #pragma unroll
    for (int i = 0; i < 5; ++i) acc[i] = sB[c0 + i];

    const float* hr = sH + r * 132;
    for (int k = 0; k < 128; ++k) {
        float hv = hr[k];
        const float* wk = sW + k * 40 + c0;
        #pragma unroll
        for (int i = 0; i < 5; ++i) acc[i] += hv * wk[i];
    }

    float m = acc[0];
    #pragma unroll
    for (int i = 1; i < 5; ++i) m = fmaxf(m, acc[i]);
    for (int off = 1; off < 8; off <<= 1) m = fmaxf(m, __shfl_xor(m, off));
    float s = 0.f;
    #pragma unroll
    for (int i = 0; i < 5; ++i) { acc[i] = expf(acc[i] - m); s += acc[i]; }
    for (int off = 1; off < 8; off <<= 1) s += __shfl_xor(s, off);
    float inv = 1.0f / s;

    int gr = row0 + r;
    if (gr < N) {
        #pragma unroll
        for (int i = 0; i < 5; ++i) out[(size_t)gr * 40 + c0 + i] = acc[i] * inv;
    }
}

// ---- launcher -----------------------------------------------------------

extern "C" void kernel_launch(void* const* d_in, const int* in_sizes, int n_in,
                              void* d_out, int out_size, void* d_ws, size_t ws_size,
                              hipStream_t stream) {
    const float* x   = (const float*)d_in[0];
    const int*   e   = (const int*)d_in[1];
    const float* W1l = (const float*)d_in[2];
    const float* b1  = (const float*)d_in[3];
    const float* W1r = (const float*)d_in[4];
    const float* W2l = (const float*)d_in[5];
    const float* b2  = (const float*)d_in[6];
    const float* W2r = (const float*)d_in[7];
    const float* W3l = (const float*)d_in[8];
    const float* b3  = (const float*)d_in[9];
    const float* W3r = (const float*)d_in[10];
    const float* Wfc = (const float*)d_in[11];
    const float* bfc = (const float*)d_in[12];
    float* out = (float*)d_out;

    const int N = NN;
    const int E = in_sizes[1] / 2;

    unsigned char* p = (unsigned char*)d_ws;
    unsigned short* xb   = (unsigned short*)p; p += (size_t)N * D * 2;
    unsigned short* h1b  = (unsigned short*)p; p += (size_t)N * D * 2;
    unsigned short* h2b  = (unsigned short*)p; p += (size_t)N * D * 2;
    unsigned short* aggb = (unsigned short*)p; p += (size_t)N * D * 2;
    unsigned char*  xf8  = (unsigned char*)p;  p += (size_t)N * D;      // aliased by h2f8
    unsigned char*  h1f8 = (unsigned char*)p;  p += (size_t)N * D;
    unsigned short* wpk  = (unsigned short*)p; p += 6 * 16384 * 2;
    float* inv_cnt = (float*)p; p += (size_t)N * 4;
    int* row_ptr = (int*)p; p += (size_t)(N + 4) * 4;
    int* cnt     = (int*)p; p += (size_t)N * 4;
    int* bukcnt  = (int*)p; p += NBUK * 4;
    int* bukbase = (int*)p; p += (NBUK + 4) * 4;
    int* bukfill = (int*)p; p += NBUK * 4;
    int* bsum    = (int*)p; p += 64 * 4;
    unsigned int* ebuk = (unsigned int*)p; p += (size_t)E * 4;
    unsigned short* csr_src = (unsigned short*)p;
    float* h3f = (float*)xb;            // overlays xb+h1b (dead by layer 3)
    unsigned char* h2f8 = xf8;          // xf8 dead after layer-1 aggregate

    unsigned short* w1lp = wpk;
    unsigned short* w1rp = wpk + 16384;
    unsigned short* w2lp = wpk + 2 * 16384;
    unsigned short* w2rp = wpk + 3 * 16384;
    unsigned short* w3lp = wpk + 4 * 16384;
    unsigned short* w3rp = wpk + 5 * 16384;

    hipMemsetAsync(bukcnt, 0, sizeof(int) * NBUK, stream);

    f32_cvt_kernel<<<(N * D / 4 + 255) / 256, 256, 0, stream>>>(x, xb, (unsigned int*)xf8,
                                                                N * D / 4);
    pack_all_kernel<<<384, 256, 0, stream>>>(W1l, W1r, W2l, W2r, W3l, W3r, wpk);

    int EB = (E + EPB - 1) / EPB;
    bucket_hist_kernel<<<EB, 256, 0, stream>>>(e, E, bukcnt);
    bucket_scan_kernel<<<1, 256, 0, stream>>>(bukcnt, bukbase, bukfill, E);
    bucket_scatter_kernel<<<EB, 256, 0, stream>>>(e, E, bukfill, ebuk);
    cnt_hist_kernel<<<NBUK, 256, 0, stream>>>(ebuk, bukbase, cnt, N);
    scan_blocks_kernel<<<NB, 256, 0, stream>>>(cnt, row_ptr, bsum, N);
    scan_bsums_kernel<<<1, 64, 0, stream>>>(bsum, NB);
    scan_add_kernel<<<NB, 256, 0, stream>>>(cnt, row_ptr, bsum, inv_cnt, N, E);
    csr_scatter_kernel<<<NBUK, 256, 0, stream>>>(ebuk, bukbase, row_ptr, csr_src, N);

    int aggBlocks = (N * 32 + 255) / 256;
    int sageBlocks = (N + 63) / 64;
    int fcBlocks = (N + 31) / 32;

    aggregate_kernel<<<aggBlocks, 256, 0, stream>>>((const unsigned int*)xf8, row_ptr,
                                                    csr_src, inv_cnt, aggb, N);
    sage_mfma_kernel<<<sageBlocks, 256, 0, stream>>>(aggb, xb, w1lp, w1rp, b1,
                                                     h1b, h1f8, nullptr, 1, N);

    aggregate_kernel<<<aggBlocks, 256, 0, stream>>>((const unsigned int*)h1f8, row_ptr,
                                                    csr_src, inv_cnt, aggb, N);
    sage_mfma_kernel<<<sageBlocks, 256, 0, stream>>>(aggb, h1b, w2lp, w2rp, b2,
                                                     h2b, h2f8, nullptr, 1, N);

    aggregate_kernel<<<aggBlocks, 256, 0, stream>>>((const unsigned int*)h2f8, row_ptr,
                                                    csr_src, inv_cnt, aggb, N);
    sage_mfma_kernel<<<sageBlocks, 256, 0, stream>>>(aggb, h2b, w3lp, w3rp, b3,
                                                     nullptr, nullptr, h3f, 0, N);

    fc_softmax_kernel<<<fcBlocks, 256, 0, stream>>>(h3f, Wfc, bfc, out, N);
}

// Round 16
// 193.913 us; speedup vs baseline: 3.1874x; 1.0519x over previous
//
#include <hip/hip_runtime.h>
#include <math.h>

#define NN 50000
#define D 128
#define NBUK 256   // dst buckets (dst>>8), covers 65536 >= N
#define EPB 4096   // edges per block in bucket passes

typedef __attribute__((ext_vector_type(8))) short bf16x8;
typedef __attribute__((ext_vector_type(4))) float f32x4;
typedef __attribute__((ext_vector_type(2))) float f32x2;

__device__ __forceinline__ float bf2f(unsigned short u) {
    union { unsigned int i; float f; } c;
    c.i = ((unsigned int)u) << 16;
    return c.f;
}
__device__ __forceinline__ unsigned short f2bf(float f) {
    union { float f; unsigned int i; } c;
    c.f = f;
    unsigned int u = c.i;
    return (unsigned short)((u + 0x7FFFu + ((u >> 16) & 1u)) >> 16);
}
__device__ __forceinline__ unsigned char f2f8(float v) {
    return (unsigned char)(__builtin_amdgcn_cvt_pk_fp8_f32(v, v, 0, false) & 0xFF);
}

// ---- merged: x fp32->bf16+fp8 convert  +  pack 6 weights to MFMA order --
// blocks [0,384): weight pack; blocks [384, 384+n4/256): x convert.

__global__ __launch_bounds__(256) void cvtpack_kernel(const float* __restrict__ x,
                                                      unsigned short* __restrict__ xb,
                                                      unsigned int* __restrict__ x8,
                                                      int n4,
                                                      const float* __restrict__ W0,
                                                      const float* __restrict__ W1,
                                                      const float* __restrict__ W2,
                                                      const float* __restrict__ W3,
                                                      const float* __restrict__ W4,
                                                      const float* __restrict__ W5,
                                                      unsigned short* __restrict__ P) {
    if (blockIdx.x < 384) {
        int i = blockIdx.x * 256 + threadIdx.x;   // 0..98303
        int w = i >> 14, j = i & 16383;
        const float* W = (w == 0) ? W0 : (w == 1) ? W1 : (w == 2) ? W2
                       : (w == 3) ? W3 : (w == 4) ? W4 : W5;
        int e = j & 7, l = (j >> 3) & 63, n = (j >> 9) & 7, ks = j >> 12;
        int k = ks * 32 + (l >> 4) * 8 + e;
        int col = n * 16 + (l & 15);
        P[i] = f2bf(W[k * D + col]);
    } else {
        int i = (blockIdx.x - 384) * 256 + threadIdx.x;
        if (i < n4) {
            float4 v = ((const float4*)x)[i];
            ushort4 o;
            o.x = f2bf(v.x); o.y = f2bf(v.y); o.z = f2bf(v.z); o.w = f2bf(v.w);
            ((ushort4*)xb)[i] = o;
            unsigned int p01 = __builtin_amdgcn_cvt_pk_fp8_f32(v.x, v.y, 0, false);
            unsigned int p23 = __builtin_amdgcn_cvt_pk_fp8_f32(v.z, v.w, 0, false);
            x8[i] = (p01 & 0xFFFFu) | (p23 << 16);
        }
    }
}

// ---- bucketed CSR build -------------------------------------------------

__global__ __launch_bounds__(256) void bucket_hist_kernel(const int* __restrict__ e, int E,
                                                          int* __restrict__ bukcnt) {
    __shared__ int h[NBUK];
    int t = threadIdx.x;
    h[t] = 0;
    __syncthreads();
    int base = blockIdx.x * EPB;
    #pragma unroll
    for (int k = 0; k < 4; ++k) {
        int idx = base + k * 1024 + t * 4;
        if (idx + 4 <= E) {
            int4 d = *(const int4*)(e + E + idx);
            atomicAdd(&h[d.x >> 8], 1);
            atomicAdd(&h[d.y >> 8], 1);
            atomicAdd(&h[d.z >> 8], 1);
            atomicAdd(&h[d.w >> 8], 1);
        } else {
            for (int i = idx; i < E; ++i) atomicAdd(&h[e[E + i] >> 8], 1);
        }
    }
    __syncthreads();
    if (h[t]) atomicAdd(&bukcnt[t], h[t]);
}

__global__ __launch_bounds__(256) void bucket_scan_kernel(const int* __restrict__ bukcnt,
                                                          int* __restrict__ bukbase,
                                                          int* __restrict__ bukfill, int E) {
    __shared__ int wsum[4], woff[4];
    int t = threadIdx.x;
    int lane = t & 63, wave = t >> 6;
    int v = bukcnt[t];
    int incl = v;
    for (int off = 1; off < 64; off <<= 1) {
        int u = __shfl_up(incl, off);
        if (lane >= off) incl += u;
    }
    if (lane == 63) wsum[wave] = incl;
    __syncthreads();
    if (t == 0) {
        int r = 0;
        #pragma unroll
        for (int w = 0; w < 4; ++w) { woff[w] = r; r += wsum[w]; }
    }
    __syncthreads();
    int excl = woff[wave] + incl - v;
    bukbase[t] = excl;
    bukfill[t] = excl;
    if (t == 255) bukbase[NBUK] = E;
}

__global__ __launch_bounds__(256) void bucket_scatter_kernel(const int* __restrict__ e, int E,
                                                             int* __restrict__ bukfill,
                                                             unsigned int* __restrict__ ebuk) {
    __shared__ int h[NBUK];
    __shared__ int res[NBUK];
    int t = threadIdx.x;
    h[t] = 0;
    __syncthreads();
    int base = blockIdx.x * EPB;
    int4 d[4];
    #pragma unroll
    for (int k = 0; k < 4; ++k) {
        int idx = base + k * 1024 + t * 4;
        if (idx + 4 <= E) {
            d[k] = *(const int4*)(e + E + idx);
        } else {
            d[k].x = (idx + 0 < E) ? e[E + idx + 0] : -1;
            d[k].y = (idx + 1 < E) ? e[E + idx + 1] : -1;
            d[k].z = (idx + 2 < E) ? e[E + idx + 2] : -1;
            d[k].w = (idx + 3 < E) ? e[E + idx + 3] : -1;
        }
        if (d[k].x >= 0) atomicAdd(&h[d[k].x >> 8], 1);
        if (d[k].y >= 0) atomicAdd(&h[d[k].y >> 8], 1);
        if (d[k].z >= 0) atomicAdd(&h[d[k].z >> 8], 1);
        if (d[k].w >= 0) atomicAdd(&h[d[k].w >> 8], 1);
    }
    __syncthreads();
    res[t] = h[t] ? atomicAdd(&bukfill[t], h[t]) : 0;
    h[t] = 0;
    __syncthreads();
    #pragma unroll
    for (int k = 0; k < 4; ++k) {
        int idx = base + k * 1024 + t * 4;
        int4 s;
        if (idx + 4 <= E) {
            s = *(const int4*)(e + idx);
        } else {
            s.x = (idx + 0 < E) ? e[idx + 0] : 0;
            s.y = (idx + 1 < E) ? e[idx + 1] : 0;
            s.z = (idx + 2 < E) ? e[idx + 2] : 0;
            s.w = (idx + 3 < E) ? e[idx + 3] : 0;
        }
        if (d[k].x >= 0) { int b = d[k].x >> 8; int r = atomicAdd(&h[b], 1);
            ebuk[res[b] + r] = (unsigned int)(s.x & 0xFFFF) | ((unsigned int)(d[k].x & 255) << 16); }
        if (d[k].y >= 0) { int b = d[k].y >> 8; int r = atomicAdd(&h[b], 1);
            ebuk[res[b] + r] = (unsigned int)(s.y & 0xFFFF) | ((unsigned int)(d[k].y & 255) << 16); }
        if (d[k].z >= 0) { int b = d[k].z >> 8; int r = atomicAdd(&h[b], 1);
            ebuk[res[b] + r] = (unsigned int)(s.z & 0xFFFF) | ((unsigned int)(d[k].z & 255) << 16); }
        if (d[k].w >= 0) { int b = d[k].w >> 8; int r = atomicAdd(&h[b], 1);
            ebuk[res[b] + r] = (unsigned int)(s.w & 0xFFFF) | ((unsigned int)(d[k].w & 255) << 16); }
    }
}

// per-bucket histogram + in-block scan -> row_ptr, inv_cnt directly.
// bucket b holds exactly nodes [256b, 256b+256): row_ptr[g] = bukbase[b] +
// prefix of counts within the bucket.

__global__ __launch_bounds__(256) void cnt_scan_kernel(const unsigned int* __restrict__ ebuk,
                                                       const int* __restrict__ bukbase,
                                                       int* __restrict__ row_ptr,
                                                       float* __restrict__ inv_cnt,
                                                       int N, int E) {
    __shared__ int c[NBUK];
    __shared__ int wsum[4], woff[4];
    int t = threadIdx.x, b = blockIdx.x;
    c[t] = 0;
    __syncthreads();
    int lo = bukbase[b], hi = bukbase[b + 1];
    for (int i = lo + t; i < hi; i += 256) atomicAdd(&c[ebuk[i] >> 16], 1);
    __syncthreads();
    int v = c[t];
    int lane = t & 63, wave = t >> 6;
    int incl = v;
    for (int off = 1; off < 64; off <<= 1) {
        int u = __shfl_up(incl, off);
        if (lane >= off) incl += u;
    }
    if (lane == 63) wsum[wave] = incl;
    __syncthreads();
    if (t == 0) {
        int r = 0;
        #pragma unroll
        for (int w = 0; w < 4; ++w) { woff[w] = r; r += wsum[w]; }
    }
    __syncthreads();
    int excl = woff[wave] + incl - v;
    int g = b * NBUK + t;
    if (g < N) {
        row_ptr[g] = bukbase[b] + excl;
        inv_cnt[g] = 1.0f / fmaxf((float)v, 1.0f);
    }
    if (g == N) row_ptr[N] = E;
}

__global__ __launch_bounds__(256) void csr_scatter_kernel(const unsigned int* __restrict__ ebuk,
                                                          const int* __restrict__ bukbase,
                                                          const int* __restrict__ row_ptr,
                                                          unsigned short* __restrict__ csr_src,
                                                          int N) {
    __shared__ int rp[NBUK];
    __shared__ int lf[NBUK];
    int t = threadIdx.x, b = blockIdx.x;
    int g = b * NBUK + t;
    rp[t] = (g < N) ? row_ptr[g] : 0;
    lf[t] = 0;
    __syncthreads();
    int lo = bukbase[b], hi = bukbase[b + 1];
    for (int i = lo + t; i < hi; i += 256) {
        unsigned int v = ebuk[i];
        int dl = v >> 16;
        int r = atomicAdd(&lf[dl], 1);
        csr_src[rp[dl] + r] = (unsigned short)(v & 0xFFFF);
    }
}

// ---- mean aggregation over fp8 rows: 32-lane group per node -------------

__device__ __forceinline__ void acc_f8(float& x, float& y, float& z, float& w,
                                       unsigned int v) {
    f32x2 lo = __builtin_amdgcn_cvt_pk_f32_fp8(v, false);
    f32x2 hi = __builtin_amdgcn_cvt_pk_f32_fp8(v, true);
    x += lo.x; y += lo.y; z += hi.x; w += hi.y;
}

__global__ __launch_bounds__(256) void aggregate_kernel(const unsigned int* __restrict__ h8,
                                                        const int* __restrict__ row_ptr,
                                                        const unsigned short* __restrict__ csr_src,
                                                        const float* __restrict__ inv_cnt,
                                                        unsigned short* __restrict__ agg, int N) {
    int node = (int)((blockIdx.x * blockDim.x + threadIdx.x) >> 5);
    int l = threadIdx.x & 31;
    if (node >= N) return;
    int beg = row_ptr[node], end = row_ptr[node + 1];
    float a0x = 0.f, a0y = 0.f, a0z = 0.f, a0w = 0.f;
    float a1x = 0.f, a1y = 0.f, a1z = 0.f, a1w = 0.f;
    for (int base = beg; base < end; base += 32) {
        int idx = 0;
        if (base + l < end) idx = csr_src[base + l];
        int n = min(32, end - base);
        int j = 0;
        for (; j + 8 <= n; j += 8) {
            int s0 = __shfl(idx, j + 0, 32);
            int s1 = __shfl(idx, j + 1, 32);
            int s2 = __shfl(idx, j + 2, 32);
            int s3 = __shfl(idx, j + 3, 32);
            int s4 = __shfl(idx, j + 4, 32);
            int s5 = __shfl(idx, j + 5, 32);
            int s6 = __shfl(idx, j + 6, 32);
            int s7 = __shfl(idx, j + 7, 32);
            unsigned int v0 = h8[(size_t)s0 * 32 + l];
            unsigned int v1 = h8[(size_t)s1 * 32 + l];
            unsigned int v2 = h8[(size_t)s2 * 32 + l];
            unsigned int v3 = h8[(size_t)s3 * 32 + l];
            unsigned int v4 = h8[(size_t)s4 * 32 + l];
            unsigned int v5 = h8[(size_t)s5 * 32 + l];
            unsigned int v6 = h8[(size_t)s6 * 32 + l];
            unsigned int v7 = h8[(size_t)s7 * 32 + l];
            acc_f8(a0x, a0y, a0z, a0w, v0);
            acc_f8(a1x, a1y, a1z, a1w, v1);
            acc_f8(a0x, a0y, a0z, a0w, v2);
            acc_f8(a1x, a1y, a1z, a1w, v3);
            acc_f8(a0x, a0y, a0z, a0w, v4);
            acc_f8(a1x, a1y, a1z, a1w, v5);
            acc_f8(a0x, a0y, a0z, a0w, v6);
            acc_f8(a1x, a1y, a1z, a1w, v7);
        }
        for (; j < n; ++j) {
            int s = __shfl(idx, j, 32);
            acc_f8(a0x, a0y, a0z, a0w, h8[(size_t)s * 32 + l]);
        }
    }
    float iv = inv_cnt[node];
    ushort4 o;
    o.x = f2bf((a0x + a1x) * iv);
    o.y = f2bf((a0y + a1y) * iv);
    o.z = f2bf((a0z + a1z) * iv);
    o.w = f2bf((a0w + a1w) * iv);
    ((ushort4*)agg)[(size_t)node * 32 + l] = o;
}

// ---- MFMA dual-GEMM + bias + L2-normalize + ReLU (layers 1-2) -----------
// C/D layout (m89): col=lane&15, row=(lane>>4)*4+reg.

__global__ __launch_bounds__(256) void sage_mfma_kernel(const unsigned short* __restrict__ aggb,
                                                        const unsigned short* __restrict__ xb,
                                                        const unsigned short* __restrict__ wlp,
                                                        const unsigned short* __restrict__ wrp,
                                                        const float* __restrict__ bl,
                                                        unsigned short* __restrict__ outb,
                                                        unsigned char* __restrict__ out8,
                                                        int N) {
    int t = threadIdx.x;
    int w = t >> 6;
    int l = t & 63;
    int rlo = l & 15;
    int khi = l >> 4;
    int row0 = blockIdx.x * 64 + w * 16;
    int rowA = row0 + rlo;
    bool okA = rowA < N;

    f32x4 acc[8];
    #pragma unroll
    for (int n = 0; n < 8; ++n) {
        float b = bl[n * 16 + rlo];
        acc[n] = (f32x4){b, b, b, b};
    }

    const short* Ap = (const short*)aggb + (size_t)(okA ? rowA : 0) * D + khi * 8;
    const short* Xp = (const short*)xb   + (size_t)(okA ? rowA : 0) * D + khi * 8;
    const short* WL = (const short*)wlp + l * 8;
    const short* WR = (const short*)wrp + l * 8;
    const bf16x8 Z = {0, 0, 0, 0, 0, 0, 0, 0};

    #pragma unroll 1
    for (int ks = 0; ks < 4; ++ks) {
        bf16x8 a = okA ? *(const bf16x8*)(Ap + ks * 32) : Z;
        #pragma unroll
        for (int n = 0; n < 8; ++n) {
            bf16x8 b = *(const bf16x8*)(WL + (ks * 8 + n) * 512);
            acc[n] = __builtin_amdgcn_mfma_f32_16x16x32_bf16(a, b, acc[n], 0, 0, 0);
        }
    }
    #pragma unroll 1
    for (int ks = 0; ks < 4; ++ks) {
        bf16x8 a = okA ? *(const bf16x8*)(Xp + ks * 32) : Z;
        #pragma unroll
        for (int n = 0; n < 8; ++n) {
            bf16x8 b = *(const bf16x8*)(WR + (ks * 8 + n) * 512);
            acc[n] = __builtin_amdgcn_mfma_f32_16x16x32_bf16(a, b, acc[n], 0, 0, 0);
        }
    }

    #pragma unroll
    for (int r = 0; r < 4; ++r) {
        float s = 0.f;
        #pragma unroll
        for (int n = 0; n < 8; ++n) s += acc[n][r] * acc[n][r];
        s += __shfl_xor(s, 1);
        s += __shfl_xor(s, 2);
        s += __shfl_xor(s, 4);
        s += __shfl_xor(s, 8);
        float inv = 1.0f / fmaxf(sqrtf(s), 1e-12f);
        int gr = row0 + khi * 4 + r;
        if (gr < N) {
            #pragma unroll
            for (int n = 0; n < 8; ++n) {
                float v = fmaxf(acc[n][r] * inv, 0.f);
                outb[(size_t)gr * D + n * 16 + rlo] = f2bf(v);
                out8[(size_t)gr * D + n * 16 + rlo] = f2f8(v);
            }
        }
    }
}

// ---- layer 3 fused: MFMA dual-GEMM + norm + FC + softmax ----------------
// h3 (64 rows) staged in LDS; Wfc in LDS; 4 threads/row x 10 cols each.

__global__ __launch_bounds__(256) void sage_mfma_fc_kernel(const unsigned short* __restrict__ aggb,
                                                           const unsigned short* __restrict__ xb,
                                                           const unsigned short* __restrict__ wlp,
                                                           const unsigned short* __restrict__ wrp,
                                                           const float* __restrict__ bl,
                                                           const float* __restrict__ Wfc,
                                                           const float* __restrict__ bfc,
                                                           float* __restrict__ out, int N) {
    __shared__ float sH[64 * 132];   // 33.8 KB
    __shared__ float sW[128 * 40];   // 20.5 KB
    __shared__ float sB[40];
    int t = threadIdx.x;
    int w = t >> 6;
    int l = t & 63;
    int rlo = l & 15;
    int khi = l >> 4;
    int row0 = blockIdx.x * 64 + w * 16;
    int rowA = row0 + rlo;
    bool okA = rowA < N;

    // stage Wfc/bfc (no sync needed until after sH writes)
    {
        const float4* W4 = (const float4*)Wfc;
        float4* sW4 = (float4*)sW;
        for (int i = t; i < 1280; i += 256) sW4[i] = W4[i];
        if (t < 40) sB[t] = bfc[t];
    }

    f32x4 acc[8];
    #pragma unroll
    for (int n = 0; n < 8; ++n) {
        float b = bl[n * 16 + rlo];
        acc[n] = (f32x4){b, b, b, b};
    }

    const short* Ap = (const short*)aggb + (size_t)(okA ? rowA : 0) * D + khi * 8;
    const short* Xp = (const short*)xb   + (size_t)(okA ? rowA : 0) * D + khi * 8;
    const short* WL = (const short*)wlp + l * 8;
    const short* WR = (const short*)wrp + l * 8;
    const bf16x8 Z = {0, 0, 0, 0, 0, 0, 0, 0};

    #pragma unroll 1
    for (int ks = 0; ks < 4; ++ks) {
        bf16x8 a = okA ? *(const bf16x8*)(Ap + ks * 32) : Z;
        #pragma unroll
        for (int n = 0; n < 8; ++n) {
            bf16x8 b = *(const bf16x8*)(WL + (ks * 8 + n) * 512);
            acc[n] = __builtin_amdgcn_mfma_f32_16x16x32_bf16(a, b, acc[n], 0, 0, 0);
        }
    }
    #pragma unroll 1
    for (int ks = 0; ks < 4; ++ks) {
        bf16x8 a = okA ? *(const bf16x8*)(Xp + ks * 32) : Z;
        #pragma unroll
        for (int n = 0; n < 8; ++n) {
            bf16x8 b = *(const bf16x8*)(WR + (ks * 8 + n) * 512);
            acc[n] = __builtin_amdgcn_mfma_f32_16x16x32_bf16(a, b, acc[n], 0, 0, 0);
        }
    }

    // norm (no relu) -> sH
    #pragma unroll
    for (int r = 0; r < 4; ++r) {
        float s = 0.f;
        #pragma unroll
        for (int n = 0; n < 8; ++n) s += acc[n][r] * acc[n][r];
        s += __shfl_xor(s, 1);
        s += __shfl_xor(s, 2);
        s += __shfl_xor(s, 4);
        s += __shfl_xor(s, 8);
        float inv = 1.0f / fmaxf(sqrtf(s), 1e-12f);
        int lr = w * 16 + khi * 4 + r;
        #pragma unroll
        for (int n = 0; n < 8; ++n)
            sH[lr * 132 + n * 16 + rlo] = acc[n][r] * inv;
    }
    __syncthreads();

    // FC + softmax: row = t>>2 (0..63), 4 threads/row, 10 cols each
    int r2 = t >> 2, sub = t & 3;
    int c0 = sub * 10;
    float fa[10];
    #pragma unroll
    for (int i = 0; i < 10; ++i) fa[i] = sB[c0 + i];
    const float* hr = sH + r2 * 132;
    for (int k = 0; k < 128; ++k) {
        float hv = hr[k];
        const float* wk = sW + k * 40 + c0;
        #pragma unroll
        for (int i = 0; i < 10; ++i) fa[i] += hv * wk[i];
    }
    float m = fa[0];
    #pragma unroll
    for (int i = 1; i < 10; ++i) m = fmaxf(m, fa[i]);
    m = fmaxf(m, __shfl_xor(m, 1));
    m = fmaxf(m, __shfl_xor(m, 2));
    float ssum = 0.f;
    #pragma unroll
    for (int i = 0; i < 10; ++i) { fa[i] = expf(fa[i] - m); ssum += fa[i]; }
    ssum += __shfl_xor(ssum, 1);
    ssum += __shfl_xor(ssum, 2);
    float inv = 1.0f / ssum;

    int gr = blockIdx.x * 64 + r2;
    if (gr < N) {
        #pragma unroll
        for (int i = 0; i < 10; ++i) out[(size_t)gr * 40 + c0 + i] = fa[i] * inv;
    }
}

// ---- launcher -----------------------------------------------------------

extern "C" void kernel_launch(void* const* d_in, const int* in_sizes, int n_in,
                              void* d_out, int out_size, void* d_ws, size_t ws_size,
                              hipStream_t stream) {
    const float* x   = (const float*)d_in[0];
    const int*   e   = (const int*)d_in[1];
    const float* W1l = (const float*)d_in[2];
    const float* b1  = (const float*)d_in[3];
    const float* W1r = (const float*)d_in[4];
    const float* W2l = (const float*)d_in[5];
    const float* b2  = (const float*)d_in[6];
    const float* W2r = (const float*)d_in[7];
    const float* W3l = (const float*)d_in[8];
    const float* b3  = (const float*)d_in[9];
    const float* W3r = (const float*)d_in[10];
    const float* Wfc = (const float*)d_in[11];
    const float* bfc = (const float*)d_in[12];
    float* out = (float*)d_out;

    const int N = NN;
    const int E = in_sizes[1] / 2;

    unsigned char* p = (unsigned char*)d_ws;
    unsigned short* xb   = (unsigned short*)p; p += (size_t)N * D * 2;
    unsigned short* h1b  = (unsigned short*)p; p += (size_t)N * D * 2;
    unsigned short* h2b  = (unsigned short*)p; p += (size_t)N * D * 2;
    unsigned short* aggb = (unsigned short*)p; p += (size_t)N * D * 2;
    unsigned char*  xf8  = (unsigned char*)p;  p += (size_t)N * D;   // reused as h2f8
    unsigned char*  h1f8 = (unsigned char*)p;  p += (size_t)N * D;
    unsigned short* wpk  = (unsigned short*)p; p += 6 * 16384 * 2;
    float* inv_cnt = (float*)p; p += (size_t)N * 4;
    int* row_ptr = (int*)p; p += (size_t)(N + 4) * 4;
    int* bukcnt  = (int*)p; p += NBUK * 4;
    int* bukbase = (int*)p; p += (NBUK + 4) * 4;
    int* bukfill = (int*)p; p += NBUK * 4;
    unsigned int* ebuk = (unsigned int*)p; p += (size_t)E * 4;
    unsigned short* csr_src = (unsigned short*)p;
    unsigned char* h2f8 = xf8;   // xf8 dead after layer-1 aggregate

    unsigned short* w1lp = wpk;
    unsigned short* w1rp = wpk + 16384;
    unsigned short* w2lp = wpk + 2 * 16384;
    unsigned short* w2rp = wpk + 3 * 16384;
    unsigned short* w3lp = wpk + 4 * 16384;
    unsigned short* w3rp = wpk + 5 * 16384;

    hipMemsetAsync(bukcnt, 0, sizeof(int) * NBUK, stream);

    int n4 = N * D / 4;
    cvtpack_kernel<<<384 + (n4 + 255) / 256, 256, 0, stream>>>(
        x, xb, (unsigned int*)xf8, n4, W1l, W1r, W2l, W2r, W3l, W3r, wpk);

    int EB = (E + EPB - 1) / EPB;
    bucket_hist_kernel<<<EB, 256, 0, stream>>>(e, E, bukcnt);
    bucket_scan_kernel<<<1, 256, 0, stream>>>(bukcnt, bukbase, bukfill, E);
    bucket_scatter_kernel<<<EB, 256, 0, stream>>>(e, E, bukfill, ebuk);
    cnt_scan_kernel<<<NBUK, 256, 0, stream>>>(ebuk, bukbase, row_ptr, inv_cnt, N, E);
    csr_scatter_kernel<<<NBUK, 256, 0, stream>>>(ebuk, bukbase, row_ptr, csr_src, N);

    int aggBlocks = (N * 32 + 255) / 256;
    int sageBlocks = (N + 63) / 64;

    aggregate_kernel<<<aggBlocks, 256, 0, stream>>>((const unsigned int*)xf8, row_ptr,
                                                    csr_src, inv_cnt, aggb, N);
    sage_mfma_kernel<<<sageBlocks, 256, 0, stream>>>(aggb, xb, w1lp, w1rp, b1,
                                                     h1b, h1f8, N);

    aggregate_kernel<<<aggBlocks, 256, 0, stream>>>((const unsigned int*)h1f8, row_ptr,
                                                    csr_src, inv_cnt, aggb, N);
    sage_mfma_kernel<<<sageBlocks, 256, 0, stream>>>(aggb, h1b, w2lp, w2rp, b2,
                                                     h2b, h2f8, N);

    aggregate_kernel<<<aggBlocks, 256, 0, stream>>>((const unsigned int*)h2f8, row_ptr,
                                                    csr_src, inv_cnt, aggb, N);
    sage_mfma_fc_kernel<<<sageBlocks, 256, 0, stream>>>(aggb, h2b, w3lp, w3rp, b3,
                                                        Wfc, bfc, out, N);
}

// Round 17
// 172.375 us; speedup vs baseline: 3.5856x; 1.1249x over previous
//
#include <hip/hip_runtime.h>
#include <math.h>

#define NN 50000
#define D 128
#define NBUK 256   // dst buckets (dst>>8), covers 65536 >= N
#define EPB 4096   // edges per block in bucket passes

typedef __attribute__((ext_vector_type(8))) short bf16x8;
typedef __attribute__((ext_vector_type(4))) float f32x4;
typedef __attribute__((ext_vector_type(2))) float f32x2;

__device__ __forceinline__ float bf2f(unsigned short u) {
    union { unsigned int i; float f; } c;
    c.i = ((unsigned int)u) << 16;
    return c.f;
}
__device__ __forceinline__ unsigned short f2bf(float f) {
    union { float f; unsigned int i; } c;
    c.f = f;
    unsigned int u = c.i;
    return (unsigned short)((u + 0x7FFFu + ((u >> 16) & 1u)) >> 16);
}
__device__ __forceinline__ unsigned char f2f8(float v) {
    return (unsigned char)(__builtin_amdgcn_cvt_pk_fp8_f32(v, v, 0, false) & 0xFF);
}

// ---- merged: weight pack (6 layer W + Wfc) + x fp32->bf16+fp8 -----------
// blocks [0,384): layer weights; [384,408): Wfc pack; [408, ...): x cvt.

__global__ __launch_bounds__(256) void cvtpack_kernel(const float* __restrict__ x,
                                                      unsigned short* __restrict__ xb,
                                                      unsigned int* __restrict__ x8,
                                                      int n4,
                                                      const float* __restrict__ W0,
                                                      const float* __restrict__ W1,
                                                      const float* __restrict__ W2,
                                                      const float* __restrict__ W3,
                                                      const float* __restrict__ W4,
                                                      const float* __restrict__ W5,
                                                      unsigned short* __restrict__ P,
                                                      const float* __restrict__ Wfc,
                                                      unsigned short* __restrict__ Pfc) {
    if (blockIdx.x < 384) {
        int i = blockIdx.x * 256 + threadIdx.x;   // 0..98303
        int w = i >> 14, j = i & 16383;
        const float* W = (w == 0) ? W0 : (w == 1) ? W1 : (w == 2) ? W2
                       : (w == 3) ? W3 : (w == 4) ? W4 : W5;
        int e = j & 7, l = (j >> 3) & 63, n = (j >> 9) & 7, ks = j >> 12;
        int k = ks * 32 + (l >> 4) * 8 + e;
        int col = n * 16 + (l & 15);
        P[i] = f2bf(W[k * D + col]);
    } else if (blockIdx.x < 408) {
        int i = (blockIdx.x - 384) * 256 + threadIdx.x;   // 0..6143
        int e = i & 7, l = (i >> 3) & 63, f = i >> 9;      // f = ks*3+n, 0..11
        int ks = f / 3, n = f - ks * 3;
        int k = ks * 32 + (l >> 4) * 8 + e;
        int col = n * 16 + (l & 15);
        Pfc[i] = (col < 40) ? f2bf(Wfc[k * 40 + col]) : (unsigned short)0;
    } else {
        int i = (blockIdx.x - 408) * 256 + threadIdx.x;
        if (i < n4) {
            float4 v = ((const float4*)x)[i];
            ushort4 o;
            o.x = f2bf(v.x); o.y = f2bf(v.y); o.z = f2bf(v.z); o.w = f2bf(v.w);
            ((ushort4*)xb)[i] = o;
            unsigned int p01 = __builtin_amdgcn_cvt_pk_fp8_f32(v.x, v.y, 0, false);
            unsigned int p23 = __builtin_amdgcn_cvt_pk_fp8_f32(v.z, v.w, 0, false);
            x8[i] = (p01 & 0xFFFFu) | (p23 << 16);
        }
    }
}

// ---- bucketed CSR build -------------------------------------------------

__global__ __launch_bounds__(256) void bucket_hist_kernel(const int* __restrict__ e, int E,
                                                          int* __restrict__ bukcnt) {
    __shared__ int h[NBUK];
    int t = threadIdx.x;
    h[t] = 0;
    __syncthreads();
    int base = blockIdx.x * EPB;
    #pragma unroll
    for (int k = 0; k < 4; ++k) {
        int idx = base + k * 1024 + t * 4;
        if (idx + 4 <= E) {
            int4 d = *(const int4*)(e + E + idx);
            atomicAdd(&h[d.x >> 8], 1);
            atomicAdd(&h[d.y >> 8], 1);
            atomicAdd(&h[d.z >> 8], 1);
            atomicAdd(&h[d.w >> 8], 1);
        } else {
            for (int i = idx; i < E; ++i) atomicAdd(&h[e[E + i] >> 8], 1);
        }
    }
    __syncthreads();
    if (h[t]) atomicAdd(&bukcnt[t], h[t]);
}

__global__ __launch_bounds__(256) void bucket_scan_kernel(const int* __restrict__ bukcnt,
                                                          int* __restrict__ bukbase,
                                                          int* __restrict__ bukfill, int E) {
    __shared__ int wsum[4], woff[4];
    int t = threadIdx.x;
    int lane = t & 63, wave = t >> 6;
    int v = bukcnt[t];
    int incl = v;
    for (int off = 1; off < 64; off <<= 1) {
        int u = __shfl_up(incl, off);
        if (lane >= off) incl += u;
    }
    if (lane == 63) wsum[wave] = incl;
    __syncthreads();
    if (t == 0) {
        int r = 0;
        #pragma unroll
        for (int w = 0; w < 4; ++w) { woff[w] = r; r += wsum[w]; }
    }
    __syncthreads();
    int excl = woff[wave] + incl - v;
    bukbase[t] = excl;
    bukfill[t] = excl;
    if (t == 255) bukbase[NBUK] = E;
}

__global__ __launch_bounds__(256) void bucket_scatter_kernel(const int* __restrict__ e, int E,
                                                             int* __restrict__ bukfill,
                                                             unsigned int* __restrict__ ebuk) {
    __shared__ int h[NBUK];
    __shared__ int res[NBUK];
    int t = threadIdx.x;
    h[t] = 0;
    __syncthreads();
    int base = blockIdx.x * EPB;
    int4 d[4];
    #pragma unroll
    for (int k = 0; k < 4; ++k) {
        int idx = base + k * 1024 + t * 4;
        if (idx + 4 <= E) {
            d[k] = *(const int4*)(e + E + idx);
        } else {
            d[k].x = (idx + 0 < E) ? e[E + idx + 0] : -1;
            d[k].y = (idx + 1 < E) ? e[E + idx + 1] : -1;
            d[k].z = (idx + 2 < E) ? e[E + idx + 2] : -1;
            d[k].w = (idx + 3 < E) ? e[E + idx + 3] : -1;
        }
        if (d[k].x >= 0) atomicAdd(&h[d[k].x >> 8], 1);
        if (d[k].y >= 0) atomicAdd(&h[d[k].y >> 8], 1);
        if (d[k].z >= 0) atomicAdd(&h[d[k].z >> 8], 1);
        if (d[k].w >= 0) atomicAdd(&h[d[k].w >> 8], 1);
    }
    __syncthreads();
    res[t] = h[t] ? atomicAdd(&bukfill[t], h[t]) : 0;
    h[t] = 0;
    __syncthreads();
    #pragma unroll
    for (int k = 0; k < 4; ++k) {
        int idx = base + k * 1024 + t * 4;
        int4 s;
        if (idx + 4 <= E) {
            s = *(const int4*)(e + idx);
        } else {
            s.x = (idx + 0 < E) ? e[idx + 0] : 0;
            s.y = (idx + 1 < E) ? e[idx + 1] : 0;
            s.z = (idx + 2 < E) ? e[idx + 2] : 0;
            s.w = (idx + 3 < E) ? e[idx + 3] : 0;
        }
        if (d[k].x >= 0) { int b = d[k].x >> 8; int r = atomicAdd(&h[b], 1);
            ebuk[res[b] + r] = (unsigned int)(s.x & 0xFFFF) | ((unsigned int)(d[k].x & 255) << 16); }
        if (d[k].y >= 0) { int b = d[k].y >> 8; int r = atomicAdd(&h[b], 1);
            ebuk[res[b] + r] = (unsigned int)(s.y & 0xFFFF) | ((unsigned int)(d[k].y & 255) << 16); }
        if (d[k].z >= 0) { int b = d[k].z >> 8; int r = atomicAdd(&h[b], 1);
            ebuk[res[b] + r] = (unsigned int)(s.z & 0xFFFF) | ((unsigned int)(d[k].z & 255) << 16); }
        if (d[k].w >= 0) { int b = d[k].w >> 8; int r = atomicAdd(&h[b], 1);
            ebuk[res[b] + r] = (unsigned int)(s.w & 0xFFFF) | ((unsigned int)(d[k].w & 255) << 16); }
    }
}

// per-bucket histogram + in-block scan -> row_ptr, inv_cnt directly.

__global__ __launch_bounds__(256) void cnt_scan_kernel(const unsigned int* __restrict__ ebuk,
                                                       const int* __restrict__ bukbase,
                                                       int* __restrict__ row_ptr,
                                                       float* __restrict__ inv_cnt,
                                                       int N, int E) {
    __shared__ int c[NBUK];
    __shared__ int wsum[4], woff[4];
    int t = threadIdx.x, b = blockIdx.x;
    c[t] = 0;
    __syncthreads();
    int lo = bukbase[b], hi = bukbase[b + 1];
    for (int i = lo + t; i < hi; i += 256) atomicAdd(&c[ebuk[i] >> 16], 1);
    __syncthreads();
    int v = c[t];
    int lane = t & 63, wave = t >> 6;
    int incl = v;
    for (int off = 1; off < 64; off <<= 1) {
        int u = __shfl_up(incl, off);
        if (lane >= off) incl += u;
    }
    if (lane == 63) wsum[wave] = incl;
    __syncthreads();
    if (t == 0) {
        int r = 0;
        #pragma unroll
        for (int w = 0; w < 4; ++w) { woff[w] = r; r += wsum[w]; }
    }
    __syncthreads();
    int excl = woff[wave] + incl - v;
    int g = b * NBUK + t;
    if (g < N) {
        row_ptr[g] = bukbase[b] + excl;
        inv_cnt[g] = 1.0f / fmaxf((float)v, 1.0f);
    }
    if (g == N) row_ptr[N] = E;
}

__global__ __launch_bounds__(256) void csr_scatter_kernel(const unsigned int* __restrict__ ebuk,
                                                          const int* __restrict__ bukbase,
                                                          const int* __restrict__ row_ptr,
                                                          unsigned short* __restrict__ csr_src,
                                                          int N) {
    __shared__ int rp[NBUK];
    __shared__ int lf[NBUK];
    int t = threadIdx.x, b = blockIdx.x;
    int g = b * NBUK + t;
    rp[t] = (g < N) ? row_ptr[g] : 0;
    lf[t] = 0;
    __syncthreads();
    int lo = bukbase[b], hi = bukbase[b + 1];
    for (int i = lo + t; i < hi; i += 256) {
        unsigned int v = ebuk[i];
        int dl = v >> 16;
        int r = atomicAdd(&lf[dl], 1);
        csr_src[rp[dl] + r] = (unsigned short)(v & 0xFFFF);
    }
}

// ---- mean aggregation over fp8 rows: 32-lane group per node -------------

__device__ __forceinline__ void acc_f8(float& x, float& y, float& z, float& w,
                                       unsigned int v) {
    f32x2 lo = __builtin_amdgcn_cvt_pk_f32_fp8(v, false);
    f32x2 hi = __builtin_amdgcn_cvt_pk_f32_fp8(v, true);
    x += lo.x; y += lo.y; z += hi.x; w += hi.y;
}

__global__ __launch_bounds__(256) void aggregate_kernel(const unsigned int* __restrict__ h8,
                                                        const int* __restrict__ row_ptr,
                                                        const unsigned short* __restrict__ csr_src,
                                                        const float* __restrict__ inv_cnt,
                                                        unsigned short* __restrict__ agg, int N) {
    int node = (int)((blockIdx.x * blockDim.x + threadIdx.x) >> 5);
    int l = threadIdx.x & 31;
    if (node >= N) return;
    int beg = row_ptr[node], end = row_ptr[node + 1];
    float a0x = 0.f, a0y = 0.f, a0z = 0.f, a0w = 0.f;
    float a1x = 0.f, a1y = 0.f, a1z = 0.f, a1w = 0.f;
    for (int base = beg; base < end; base += 32) {
        int idx = 0;
        if (base + l < end) idx = csr_src[base + l];
        int n = min(32, end - base);
        int j = 0;
        for (; j + 8 <= n; j += 8) {
            int s0 = __shfl(idx, j + 0, 32);
            int s1 = __shfl(idx, j + 1, 32);
            int s2 = __shfl(idx, j + 2, 32);
            int s3 = __shfl(idx, j + 3, 32);
            int s4 = __shfl(idx, j + 4, 32);
            int s5 = __shfl(idx, j + 5, 32);
            int s6 = __shfl(idx, j + 6, 32);
            int s7 = __shfl(idx, j + 7, 32);
            unsigned int v0 = h8[(size_t)s0 * 32 + l];
            unsigned int v1 = h8[(size_t)s1 * 32 + l];
            unsigned int v2 = h8[(size_t)s2 * 32 + l];
            unsigned int v3 = h8[(size_t)s3 * 32 + l];
            unsigned int v4 = h8[(size_t)s4 * 32 + l];
            unsigned int v5 = h8[(size_t)s5 * 32 + l];
            unsigned int v6 = h8[(size_t)s6 * 32 + l];
            unsigned int v7 = h8[(size_t)s7 * 32 + l];
            acc_f8(a0x, a0y, a0z, a0w, v0);
            acc_f8(a1x, a1y, a1z, a1w, v1);
            acc_f8(a0x, a0y, a0z, a0w, v2);
            acc_f8(a1x, a1y, a1z, a1w, v3);
            acc_f8(a0x, a0y, a0z, a0w, v4);
            acc_f8(a1x, a1y, a1z, a1w, v5);
            acc_f8(a0x, a0y, a0z, a0w, v6);
            acc_f8(a1x, a1y, a1z, a1w, v7);
        }
        for (; j < n; ++j) {
            int s = __shfl(idx, j, 32);
            acc_f8(a0x, a0y, a0z, a0w, h8[(size_t)s * 32 + l]);
        }
    }
    float iv = inv_cnt[node];
    ushort4 o;
    o.x = f2bf((a0x + a1x) * iv);
    o.y = f2bf((a0y + a1y) * iv);
    o.z = f2bf((a0z + a1z) * iv);
    o.w = f2bf((a0w + a1w) * iv);
    ((ushort4*)agg)[(size_t)node * 32 + l] = o;
}

// ---- MFMA dual-GEMM + bias + L2-normalize + ReLU (layers 1-2) -----------
// C/D layout (m89): col=lane&15, row=(lane>>4)*4+reg.

__global__ __launch_bounds__(256) void sage_mfma_kernel(const unsigned short* __restrict__ aggb,
                                                        const unsigned short* __restrict__ xb,
                                                        const unsigned short* __restrict__ wlp,
                                                        const unsigned short* __restrict__ wrp,
                                                        const float* __restrict__ bl,
                                                        unsigned short* __restrict__ outb,
                                                        unsigned char* __restrict__ out8,
                                                        int N) {
    int t = threadIdx.x;
    int w = t >> 6;
    int l = t & 63;
    int rlo = l & 15;
    int khi = l >> 4;
    int row0 = blockIdx.x * 64 + w * 16;
    int rowA = row0 + rlo;
    bool okA = rowA < N;

    f32x4 acc[8];
    #pragma unroll
    for (int n = 0; n < 8; ++n) {
        float b = bl[n * 16 + rlo];
        acc[n] = (f32x4){b, b, b, b};
    }

    const short* Ap = (const short*)aggb + (size_t)(okA ? rowA : 0) * D + khi * 8;
    const short* Xp = (const short*)xb   + (size_t)(okA ? rowA : 0) * D + khi * 8;
    const short* WL = (const short*)wlp + l * 8;
    const short* WR = (const short*)wrp + l * 8;
    const bf16x8 Z = {0, 0, 0, 0, 0, 0, 0, 0};

    #pragma unroll 1
    for (int ks = 0; ks < 4; ++ks) {
        bf16x8 a = okA ? *(const bf16x8*)(Ap + ks * 32) : Z;
        #pragma unroll
        for (int n = 0; n < 8; ++n) {
            bf16x8 b = *(const bf16x8*)(WL + (ks * 8 + n) * 512);
            acc[n] = __builtin_amdgcn_mfma_f32_16x16x32_bf16(a, b, acc[n], 0, 0, 0);
        }
    }
    #pragma unroll 1
    for (int ks = 0; ks < 4; ++ks) {
        bf16x8 a = okA ? *(const bf16x8*)(Xp + ks * 32) : Z;
        #pragma unroll
        for (int n = 0; n < 8; ++n) {
            bf16x8 b = *(const bf16x8*)(WR + (ks * 8 + n) * 512);
            acc[n] = __builtin_amdgcn_mfma_f32_16x16x32_bf16(a, b, acc[n], 0, 0, 0);
        }
    }

    #pragma unroll
    for (int r = 0; r < 4; ++r) {
        float s = 0.f;
        #pragma unroll
        for (int n = 0; n < 8; ++n) s += acc[n][r] * acc[n][r];
        s += __shfl_xor(s, 1);
        s += __shfl_xor(s, 2);
        s += __shfl_xor(s, 4);
        s += __shfl_xor(s, 8);
        float inv = 1.0f / fmaxf(sqrtf(s), 1e-12f);
        int gr = row0 + khi * 4 + r;
        if (gr < N) {
            #pragma unroll
            for (int n = 0; n < 8; ++n) {
                float v = fmaxf(acc[n][r] * inv, 0.f);
                outb[(size_t)gr * D + n * 16 + rlo] = f2bf(v);
                out8[(size_t)gr * D + n * 16 + rlo] = f2f8(v);
            }
        }
    }
}

// ---- layer 3 fused: MFMA dual-GEMM + norm + MFMA FC + softmax -----------
// h3 (bf16) staged in wave-local LDS rows; FC = 64x128 @ 128x48 (cols>=40
// zero-padded in packed Wfc) via 12 MFMAs/wave; bias by acc init; pad cols
// masked from softmax. No cross-wave deps -> no __syncthreads.

#define SH_STRIDE 136

__global__ __launch_bounds__(256) void sage_mfma_fc_kernel(const unsigned short* __restrict__ aggb,
                                                           const unsigned short* __restrict__ xb,
                                                           const unsigned short* __restrict__ wlp,
                                                           const unsigned short* __restrict__ wrp,
                                                           const float* __restrict__ bl,
                                                           const unsigned short* __restrict__ wfcp,
                                                           const float* __restrict__ bfc,
                                                           float* __restrict__ out, int N) {
    __shared__ unsigned short sH[64 * SH_STRIDE];   // 17.4 KB, bf16 h3
    int t = threadIdx.x;
    int w = t >> 6;
    int l = t & 63;
    int rlo = l & 15;
    int khi = l >> 4;
    int row0 = blockIdx.x * 64 + w * 16;
    int rowA = row0 + rlo;
    bool okA = rowA < N;

    f32x4 acc[8];
    #pragma unroll
    for (int n = 0; n < 8; ++n) {
        float b = bl[n * 16 + rlo];
        acc[n] = (f32x4){b, b, b, b};
    }

    const short* Ap = (const short*)aggb + (size_t)(okA ? rowA : 0) * D + khi * 8;
    const short* Xp = (const short*)xb   + (size_t)(okA ? rowA : 0) * D + khi * 8;
    const short* WL = (const short*)wlp + l * 8;
    const short* WR = (const short*)wrp + l * 8;
    const bf16x8 Z = {0, 0, 0, 0, 0, 0, 0, 0};

    #pragma unroll 1
    for (int ks = 0; ks < 4; ++ks) {
        bf16x8 a = okA ? *(const bf16x8*)(Ap + ks * 32) : Z;
        #pragma unroll
        for (int n = 0; n < 8; ++n) {
            bf16x8 b = *(const bf16x8*)(WL + (ks * 8 + n) * 512);
            acc[n] = __builtin_amdgcn_mfma_f32_16x16x32_bf16(a, b, acc[n], 0, 0, 0);
        }
    }
    #pragma unroll 1
    for (int ks = 0; ks < 4; ++ks) {
        bf16x8 a = okA ? *(const bf16x8*)(Xp + ks * 32) : Z;
        #pragma unroll
        for (int n = 0; n < 8; ++n) {
            bf16x8 b = *(const bf16x8*)(WR + (ks * 8 + n) * 512);
            acc[n] = __builtin_amdgcn_mfma_f32_16x16x32_bf16(a, b, acc[n], 0, 0, 0);
        }
    }

    // norm (no relu) -> wave-local LDS rows as bf16
    #pragma unroll
    for (int r = 0; r < 4; ++r) {
        float s = 0.f;
        #pragma unroll
        for (int n = 0; n < 8; ++n) s += acc[n][r] * acc[n][r];
        s += __shfl_xor(s, 1);
        s += __shfl_xor(s, 2);
        s += __shfl_xor(s, 4);
        s += __shfl_xor(s, 8);
        float inv = 1.0f / fmaxf(sqrtf(s), 1e-12f);
        int lr = w * 16 + khi * 4 + r;
        #pragma unroll
        for (int n = 0; n < 8; ++n)
            sH[lr * SH_STRIDE + n * 16 + rlo] = f2bf(acc[n][r] * inv);
    }
    // wave-local: writes above are only read by the same wave below.

    // FC: A-frag from sH rows [w*16, w*16+16), B = packed Wfc (48 cols)
    f32x4 fa[3];
    #pragma unroll
    for (int n = 0; n < 3; ++n) {
        int col = n * 16 + rlo;
        float b = (col < 40) ? bfc[col] : 0.f;
        fa[n] = (f32x4){b, b, b, b};
    }
    const short* WF = (const short*)wfcp + l * 8;
    const unsigned short* hrow = sH + (w * 16 + rlo) * SH_STRIDE + khi * 8;
    #pragma unroll
    for (int ks = 0; ks < 4; ++ks) {
        bf16x8 a = *(const bf16x8*)(hrow + ks * 32);
        #pragma unroll
        for (int n = 0; n < 3; ++n) {
            bf16x8 b = *(const bf16x8*)(WF + (ks * 3 + n) * 512);
            fa[n] = __builtin_amdgcn_mfma_f32_16x16x32_bf16(a, b, fa[n], 0, 0, 0);
        }
    }

    // softmax per row over 40 valid cols; lane holds cols n*16+rlo
    bool v2 = (rlo < 8);   // col 32+rlo < 40
    #pragma unroll
    for (int r = 0; r < 4; ++r) {
        float m = fmaxf(fa[0][r], fa[1][r]);
        if (v2) m = fmaxf(m, fa[2][r]);
        m = fmaxf(m, __shfl_xor(m, 1));
        m = fmaxf(m, __shfl_xor(m, 2));
        m = fmaxf(m, __shfl_xor(m, 4));
        m = fmaxf(m, __shfl_xor(m, 8));
        float e0 = expf(fa[0][r] - m);
        float e1 = expf(fa[1][r] - m);
        float e2 = v2 ? expf(fa[2][r] - m) : 0.f;
        float s = e0 + e1 + e2;
        s += __shfl_xor(s, 1);
        s += __shfl_xor(s, 2);
        s += __shfl_xor(s, 4);
        s += __shfl_xor(s, 8);
        float inv = 1.0f / s;
        int gr = row0 + khi * 4 + r;
        if (gr < N) {
            out[(size_t)gr * 40 + rlo]      = e0 * inv;
            out[(size_t)gr * 40 + 16 + rlo] = e1 * inv;
            if (v2) out[(size_t)gr * 40 + 32 + rlo] = e2 * inv;
        }
    }
}

// ---- launcher -----------------------------------------------------------

extern "C" void kernel_launch(void* const* d_in, const int* in_sizes, int n_in,
                              void* d_out, int out_size, void* d_ws, size_t ws_size,
                              hipStream_t stream) {
    const float* x   = (const float*)d_in[0];
    const int*   e   = (const int*)d_in[1];
    const float* W1l = (const float*)d_in[2];
    const float* b1  = (const float*)d_in[3];
    const float* W1r = (const float*)d_in[4];
    const float* W2l = (const float*)d_in[5];
    const float* b2  = (const float*)d_in[6];
    const float* W2r = (const float*)d_in[7];
    const float* W3l = (const float*)d_in[8];
    const float* b3  = (const float*)d_in[9];
    const float* W3r = (const float*)d_in[10];
    const float* Wfc = (const float*)d_in[11];
    const float* bfc = (const float*)d_in[12];
    float* out = (float*)d_out;

    const int N = NN;
    const int E = in_sizes[1] / 2;

    unsigned char* p = (unsigned char*)d_ws;
    unsigned short* xb   = (unsigned short*)p; p += (size_t)N * D * 2;
    unsigned short* h1b  = (unsigned short*)p; p += (size_t)N * D * 2;
    unsigned short* h2b  = (unsigned short*)p; p += (size_t)N * D * 2;
    unsigned short* aggb = (unsigned short*)p; p += (size_t)N * D * 2;
    unsigned char*  xf8  = (unsigned char*)p;  p += (size_t)N * D;   // reused as h2f8
    unsigned char*  h1f8 = (unsigned char*)p;  p += (size_t)N * D;
    unsigned short* wpk  = (unsigned short*)p; p += 6 * 16384 * 2;
    unsigned short* wfcp = (unsigned short*)p; p += 6144 * 2;
    float* inv_cnt = (float*)p; p += (size_t)N * 4;
    int* row_ptr = (int*)p; p += (size_t)(N + 4) * 4;
    int* bukcnt  = (int*)p; p += NBUK * 4;
    int* bukbase = (int*)p; p += (NBUK + 4) * 4;
    int* bukfill = (int*)p; p += NBUK * 4;
    unsigned int* ebuk = (unsigned int*)p; p += (size_t)E * 4;
    unsigned short* csr_src = (unsigned short*)p;
    unsigned char* h2f8 = xf8;   // xf8 dead after layer-1 aggregate

    unsigned short* w1lp = wpk;
    unsigned short* w1rp = wpk + 16384;
    unsigned short* w2lp = wpk + 2 * 16384;
    unsigned short* w2rp = wpk + 3 * 16384;
    unsigned short* w3lp = wpk + 4 * 16384;
    unsigned short* w3rp = wpk + 5 * 16384;

    hipMemsetAsync(bukcnt, 0, sizeof(int) * NBUK, stream);

    int n4 = N * D / 4;
    cvtpack_kernel<<<408 + (n4 + 255) / 256, 256, 0, stream>>>(
        x, xb, (unsigned int*)xf8, n4, W1l, W1r, W2l, W2r, W3l, W3r, wpk, Wfc, wfcp);

    int EB = (E + EPB - 1) / EPB;
    bucket_hist_kernel<<<EB, 256, 0, stream>>>(e, E, bukcnt);
    bucket_scan_kernel<<<1, 256, 0, stream>>>(bukcnt, bukbase, bukfill, E);
    bucket_scatter_kernel<<<EB, 256, 0, stream>>>(e, E, bukfill, ebuk);
    cnt_scan_kernel<<<NBUK, 256, 0, stream>>>(ebuk, bukbase, row_ptr, inv_cnt, N, E);
    csr_scatter_kernel<<<NBUK, 256, 0, stream>>>(ebuk, bukbase, row_ptr, csr_src, N);

    int aggBlocks = (N * 32 + 255) / 256;
    int sageBlocks = (N + 63) / 64;

    aggregate_kernel<<<aggBlocks, 256, 0, stream>>>((const unsigned int*)xf8, row_ptr,
                                                    csr_src, inv_cnt, aggb, N);
    sage_mfma_kernel<<<sageBlocks, 256, 0, stream>>>(aggb, xb, w1lp, w1rp, b1,
                                                     h1b, h1f8, N);

    aggregate_kernel<<<aggBlocks, 256, 0, stream>>>((const unsigned int*)h1f8, row_ptr,
                                                    csr_src, inv_cnt, aggb, N);
    sage_mfma_kernel<<<sageBlocks, 256, 0, stream>>>(aggb, h1b, w2lp, w2rp, b2,
                                                     h2b, h2f8, N);

    aggregate_kernel<<<aggBlocks, 256, 0, stream>>>((const unsigned int*)h2f8, row_ptr,
                                                    csr_src, inv_cnt, aggb, N);
    sage_mfma_fc_kernel<<<sageBlocks, 256, 0, stream>>>(aggb, h2b, w3lp, w3rp, b3,
                                                        wfcp, bfc, out, N);
}